// Round 2
// baseline (1107.833 us; speedup 1.0000x reference)
//
#include <hip/hip_runtime.h>
#include <stdint.h>

#define N_NODES 10000
#define N_EDGES 160000

typedef __attribute__((ext_vector_type(8))) short bf16x8;
typedef __attribute__((ext_vector_type(4))) float f32x4;
typedef __attribute__((ext_vector_type(4))) unsigned short ushort4v;

__device__ __forceinline__ unsigned short f2bf(float f){
  union { float f; unsigned u; } v; v.f = f;
  unsigned u = v.u;
  u += 0x7fffu + ((u >> 16) & 1u);       // round-to-nearest-even
  return (unsigned short)(u >> 16);
}
__device__ __forceinline__ float bf2f(unsigned short h){
  union { unsigned u; float f; } v; v.u = ((unsigned)h) << 16; return v.f;
}
__device__ __forceinline__ int clampi(int v){
  return v < 0 ? 0 : (v >= N_NODES ? N_NODES - 1 : v);
}

// ---------------- weight transpose + bf16 convert ----------------
struct TJob { const float* in; unsigned short* out; int K; int N; int row0; int ld; };
struct TJobs { TJob j[12]; };

__global__ __launch_bounds__(256) void prep_weights(TJobs jobs){
  TJob jb = jobs.j[blockIdx.y];
  int total = jb.K * jb.N;
  int i = blockIdx.x * 256 + threadIdx.x;
  if (i >= total) return;
  int n = i / jb.K;
  int k = i - n * jb.K;
  jb.out[(size_t)n * jb.K + k] = f2bf(jb.in[(size_t)(jb.row0 + k) * jb.ld + n]);
}

// ---- 4x4-fragment MFMA block over a 64x(256-chunk) LDS tile --------------
// A: LDS [64 rows][256 bf16], XOR-swizzled: byte = row*512 + (colbyte ^ ((row&7)<<4))
// Wt: row-major [outCols][wstride] bf16 (pre-transposed weights), already offset
//     to this 256-col block and K-chunk. Wave w computes cols w*64..w*64+63.
__device__ __forceinline__ void mfma_tiles(const unsigned short* __restrict__ A,
                                           const unsigned short* __restrict__ Wt,
                                           int wstride, int l, int w, f32x4 acc[4][4])
{
  #pragma unroll
  for (int ks = 0; ks < 8; ks++){
    const int kb = ks * 64 + ((l >> 4) << 4);     // byte offset of this lane's 8 bf16
    bf16x8 a[4];
    #pragma unroll
    for (int mi = 0; mi < 4; mi++){
      const int row = mi * 16 + (l & 15);
      a[mi] = *(const bf16x8*)((const char*)A + row * 512 + (kb ^ ((row & 7) << 4)));
    }
    #pragma unroll
    for (int ni = 0; ni < 4; ni++){
      const unsigned short* bp = Wt + (size_t)((w * 4 + ni) * 16 + (l & 15)) * wstride;
      bf16x8 b = *(const bf16x8*)((const char*)bp + kb);
      #pragma unroll
      for (int mi = 0; mi < 4; mi++)
        acc[mi][ni] = __builtin_amdgcn_mfma_f32_16x16x32_bf16(a[mi], b, acc[mi][ni], 0, 0, 0);
    }
  }
}

// ---------------- generic node GEMM: C = act(A1|A2 @ Wt + bias) ----------------
__global__ __launch_bounds__(256) void gemm_nodes(
    const float* __restrict__ A1, int K1,
    const float* __restrict__ A2, int K2,
    const unsigned short* __restrict__ Wt,   // [NcTot][Ktot]
    const float* __restrict__ bias,
    float* __restrict__ C, int NcTot, int relu)
{
  __shared__ __align__(16) unsigned short As[64 * 256];
  const int t = threadIdx.x, w = t >> 6, l = t & 63;
  const int rowBase = blockIdx.x * 64;
  const int bc = blockIdx.y;
  const int Ktot = K1 + K2;
  f32x4 acc[4][4] = {};
  for (int kc = 0; kc < Ktot; kc += 256){
    __syncthreads();
    {
      const int r = t >> 2, q = t & 3;
      int rg = rowBase + r; if (rg >= N_NODES) rg = N_NODES - 1;
      const float* src = (kc < K1) ? (A1 + (size_t)rg * K1 + kc)
                                   : (A2 + (size_t)rg * K2 + (kc - K1));
      #pragma unroll
      for (int u = 0; u < 16; u++){
        const int cb = q * 128 + u * 8;
        f32x4 v = *(const f32x4*)(src + q * 64 + u * 4);
        ushort4v h; h[0] = f2bf(v[0]); h[1] = f2bf(v[1]); h[2] = f2bf(v[2]); h[3] = f2bf(v[3]);
        *(ushort4v*)((char*)As + r * 512 + (cb ^ ((r & 7) << 4))) = h;
      }
    }
    __syncthreads();
    mfma_tiles(As, Wt + (size_t)(bc * 256) * Ktot + kc, Ktot, l, w, acc);
  }
  #pragma unroll
  for (int mi = 0; mi < 4; mi++)
  #pragma unroll
  for (int ni = 0; ni < 4; ni++){
    const int colAbs = bc * 256 + (w * 4 + ni) * 16 + (l & 15);
    const float bv = bias ? bias[colAbs] : 0.f;
    #pragma unroll
    for (int r = 0; r < 4; r++){
      const int rowg = rowBase + mi * 16 + (l >> 4) * 4 + r;
      if (rowg < N_NODES){
        float v = acc[mi][ni][r] + bv;
        if (relu) v = fmaxf(v, 0.f);
        C[(size_t)rowg * NcTot + colAbs] = v;
      }
    }
  }
}

// ---------------- layer-0 fused edge pass ----------------
// EH = relu(pA0[src] + pB0[dst] + ea@W1c + b1)      (built elementwise)
// ea1 = EH @ e_w2_0 + b2                            (MFMA, stored to global bf16)
// msg = relu(ea1 @ Wm_e + pM0[src] + bm); atomic-add into S[dst], count into CNT
__global__ __launch_bounds__(256) void edge_pass0(
    const int* __restrict__ ei,              // int32! harness converts int64 -> int32
    const float* __restrict__ ea,
    const float* __restrict__ P0,            // [N][768] = pA0|pB0|pM0
    const float* __restrict__ W1c,           // [6][256] (= e_w1_0 + 1024*256)
    const float* __restrict__ b1,
    const unsigned short* __restrict__ Wt_ew2,
    const float* __restrict__ b2,
    const unsigned short* __restrict__ Wt_wme,
    const float* __restrict__ bm,
    unsigned short* __restrict__ EA1,
    float* __restrict__ S,
    float* __restrict__ CNT)
{
  __shared__ __align__(16) unsigned short B1[64 * 256];
  __shared__ __align__(16) unsigned short B2[64 * 256];
  const int t = threadIdx.x, w = t >> 6, l = t & 63;
  const int e0 = blockIdx.x * 64;
  if (t < 64){
    int dv = clampi(ei[N_EDGES + e0 + t]);
    atomicAdd(&CNT[dv], 1.0f);
  }
  // step 1: EH -> B1
  {
    const int r = t >> 2, q = t & 3;
    const int e = e0 + r;
    const int sv = clampi(ei[e]);
    const int dv = clampi(ei[N_EDGES + e]);
    const float* pa = P0 + (size_t)sv * 768;
    const float* pb = P0 + (size_t)dv * 768 + 256;
    float eav[6];
    #pragma unroll
    for (int k = 0; k < 6; k++) eav[k] = ea[(size_t)e * 6 + k];
    #pragma unroll
    for (int u = 0; u < 16; u++){
      const int c = q * 64 + u * 4;
      f32x4 va  = *(const f32x4*)(pa + c);
      f32x4 vb  = *(const f32x4*)(pb + c);
      f32x4 vb1 = *(const f32x4*)(b1 + c);
      ushort4v h;
      #pragma unroll
      for (int j = 0; j < 4; j++){
        float v = va[j] + vb[j] + vb1[j];
        #pragma unroll
        for (int k = 0; k < 6; k++) v += eav[k] * W1c[k * 256 + c + j];
        h[j] = f2bf(fmaxf(v, 0.f));
      }
      *(ushort4v*)((char*)B1 + r * 512 + ((2 * c) ^ ((r & 7) << 4))) = h;
    }
  }
  __syncthreads();
  // GEMM1: ea1 -> B2
  {
    f32x4 acc[4][4] = {};
    mfma_tiles(B1, Wt_ew2, 256, l, w, acc);
    #pragma unroll
    for (int mi = 0; mi < 4; mi++)
    #pragma unroll
    for (int ni = 0; ni < 4; ni++){
      const int col = (w * 4 + ni) * 16 + (l & 15);
      const float bb = b2[col];
      #pragma unroll
      for (int r = 0; r < 4; r++){
        const int row = mi * 16 + (l >> 4) * 4 + r;
        *(unsigned short*)((char*)B2 + row * 512 + ((2 * col) ^ ((row & 7) << 4)))
            = f2bf(acc[mi][ni][r] + bb);
      }
    }
  }
  __syncthreads();
  // coalesced copy B2 -> EA1 (global)
  {
    const int r = t >> 2, q = t & 3;
    char* gdst = (char*)EA1 + (size_t)(e0 + r) * 512 + q * 128;
    #pragma unroll
    for (int u = 0; u < 8; u++){
      const int cb = q * 128 + u * 16;
      *(bf16x8*)(gdst + u * 16) =
        *(const bf16x8*)((const char*)B2 + r * 512 + (cb ^ ((r & 7) << 4)));
    }
  }
  // GEMM2: msg + atomic scatter
  {
    f32x4 acc[4][4] = {};
    mfma_tiles(B2, Wt_wme, 256, l, w, acc);
    #pragma unroll
    for (int mi = 0; mi < 4; mi++)
    #pragma unroll
    for (int ni = 0; ni < 4; ni++){
      const int col = (w * 4 + ni) * 16 + (l & 15);
      const float bb = bm[col];
      #pragma unroll
      for (int r = 0; r < 4; r++){
        const int row = mi * 16 + (l >> 4) * 4 + r;
        const int e = e0 + row;
        const int sv = clampi(ei[e]);
        const int dv = clampi(ei[N_EDGES + e]);
        float v = acc[mi][ni][r] + bb + P0[(size_t)sv * 768 + 512 + col];
        v = fmaxf(v, 0.f);
        atomicAdd(&S[(size_t)dv * 256 + col], v);
      }
    }
  }
}

// ---------------- mean normalize ----------------
__global__ __launch_bounds__(256) void norm_s(float* __restrict__ S, const float* __restrict__ CNT){
  const int i = blockIdx.x * 256 + threadIdx.x;
  const float c = fmaxf(CNT[i >> 8], 1.f);
  S[i] = S[i] / c;
}

// ---------------- layer-1 fused edge pass + predictor head ----------------
// eh1 = relu(ea1 @ W1c1 + pA1[src] + pB1[dst] + b1)
// ea2 = eh1 @ e_w2_1 + b2 + ea1
// out = relu(ea2 @ p_w1 + p_b1) . p_w2 + p_b2
__global__ __launch_bounds__(256) void edge_pass1(
    const int* __restrict__ ei,              // int32
    const unsigned short* __restrict__ EA1,
    const float* __restrict__ P1,            // [N][512] = pA1|pB1
    const float* __restrict__ b1,            // e_b1_1
    const unsigned short* __restrict__ Wt_w1c,
    const unsigned short* __restrict__ Wt_ew2,
    const float* __restrict__ b2,            // e_b2_1
    const unsigned short* __restrict__ Wt_pw1,
    const float* __restrict__ pb1,
    const float* __restrict__ pw2,
    const float* __restrict__ pb2,
    float* __restrict__ out)
{
  __shared__ __align__(16) unsigned short B1[64 * 256];
  __shared__ __align__(16) unsigned short B2[64 * 256];
  float* partial = (float*)B2;               // aliased after B2's last use
  const int t = threadIdx.x, w = t >> 6, l = t & 63;
  const int e0 = blockIdx.x * 64;
  // load ea1 tile -> B1 (swizzled)
  {
    const int r = t >> 2, q = t & 3;
    const char* gsrc = (const char*)EA1 + (size_t)(e0 + r) * 512 + q * 128;
    #pragma unroll
    for (int u = 0; u < 8; u++){
      const int cb = q * 128 + u * 16;
      *(bf16x8*)((char*)B1 + r * 512 + (cb ^ ((r & 7) << 4))) = *(const bf16x8*)(gsrc + u * 16);
    }
  }
  __syncthreads();
  // GEMM_a: eh1 -> B2
  {
    f32x4 acc[4][4] = {};
    mfma_tiles(B1, Wt_w1c, 256, l, w, acc);
    #pragma unroll
    for (int mi = 0; mi < 4; mi++)
    #pragma unroll
    for (int ni = 0; ni < 4; ni++){
      const int col = (w * 4 + ni) * 16 + (l & 15);
      const float bb = b1[col];
      #pragma unroll
      for (int r = 0; r < 4; r++){
        const int row = mi * 16 + (l >> 4) * 4 + r;
        const int e = e0 + row;
        const int sv = clampi(ei[e]);
        const int dv = clampi(ei[N_EDGES + e]);
        float v = acc[mi][ni][r] + bb + P1[(size_t)sv * 512 + col] + P1[(size_t)dv * 512 + 256 + col];
        *(unsigned short*)((char*)B2 + row * 512 + ((2 * col) ^ ((row & 7) << 4)))
            = f2bf(fmaxf(v, 0.f));
      }
    }
  }
  __syncthreads();
  // GEMM_b: ea2 = eh1 @ W2 + b2 + ea1 -> B1 (in place over ea1)
  {
    f32x4 acc[4][4] = {};
    mfma_tiles(B2, Wt_ew2, 256, l, w, acc);
    #pragma unroll
    for (int mi = 0; mi < 4; mi++)
    #pragma unroll
    for (int ni = 0; ni < 4; ni++){
      const int col = (w * 4 + ni) * 16 + (l & 15);
      const float bb = b2[col];
      #pragma unroll
      for (int r = 0; r < 4; r++){
        const int row = mi * 16 + (l >> 4) * 4 + r;
        unsigned short* p = (unsigned short*)((char*)B1 + row * 512 + ((2 * col) ^ ((row & 7) << 4)));
        float v = acc[mi][ni][r] + bb + bf2f(*p);
        *p = f2bf(v);
      }
    }
  }
  __syncthreads();
  // GEMM_c: h = relu(ea2 @ p_w1 + pb1); rowsum(h * pw2)
  {
    f32x4 acc[4][4] = {};
    mfma_tiles(B1, Wt_pw1, 256, l, w, acc);
    float rs[4][4];
    #pragma unroll
    for (int mi = 0; mi < 4; mi++)
      #pragma unroll
      for (int r = 0; r < 4; r++) rs[mi][r] = 0.f;
    #pragma unroll
    for (int mi = 0; mi < 4; mi++)
    #pragma unroll
    for (int ni = 0; ni < 4; ni++){
      const int col = (w * 4 + ni) * 16 + (l & 15);
      const float pb = pb1[col];
      const float pw = pw2[col];
      #pragma unroll
      for (int r = 0; r < 4; r++)
        rs[mi][r] += fmaxf(acc[mi][ni][r] + pb, 0.f) * pw;
    }
    #pragma unroll
    for (int off = 1; off < 16; off <<= 1){
      #pragma unroll
      for (int mi = 0; mi < 4; mi++)
        #pragma unroll
        for (int r = 0; r < 4; r++)
          rs[mi][r] += __shfl_xor(rs[mi][r], off);
    }
    if ((l & 15) == 0){
      #pragma unroll
      for (int mi = 0; mi < 4; mi++)
        #pragma unroll
        for (int r = 0; r < 4; r++)
          partial[w * 64 + mi * 16 + (l >> 4) * 4 + r] = rs[mi][r];
    }
  }
  __syncthreads();
  if (t < 64)
    out[e0 + t] = partial[t] + partial[64 + t] + partial[128 + t] + partial[192 + t] + pb2[0];
}

// ---------------- host ----------------
extern "C" void kernel_launch(void* const* d_in, const int* in_sizes, int n_in,
                              void* d_out, int out_size, void* d_ws, size_t ws_size,
                              hipStream_t stream)
{
  const float* x      = (const float*)d_in[0];
  const int* ei       = (const int*)d_in[1];        // int32 per harness contract
  const float* eattr  = (const float*)d_in[2];
  const float* e_w1_0 = (const float*)d_in[3];
  const float* e_b1_0 = (const float*)d_in[4];
  const float* e_w2_0 = (const float*)d_in[5];
  const float* e_b2_0 = (const float*)d_in[6];
  const float* n_wm_0 = (const float*)d_in[7];
  const float* n_bm_0 = (const float*)d_in[8];
  const float* n_w1_0 = (const float*)d_in[9];
  const float* n_b1_0 = (const float*)d_in[10];
  const float* n_w2_0 = (const float*)d_in[11];
  const float* n_b2_0 = (const float*)d_in[12];
  const float* e_w1_1 = (const float*)d_in[13];
  const float* e_b1_1 = (const float*)d_in[14];
  const float* e_w2_1 = (const float*)d_in[15];
  const float* e_b2_1 = (const float*)d_in[16];
  // d_in[17..22] (layer-1 node model) are dead code for the output
  const float* p_w1   = (const float*)d_in[23];
  const float* p_b1   = (const float*)d_in[24];
  const float* p_w2   = (const float*)d_in[25];
  const float* p_b2   = (const float*)d_in[26];
  float* out = (float*)d_out;

  char* base = (char*)d_ws;
  size_t off = 0;
  auto take = [&](size_t bytes)->void*{
    void* p = base + off;
    off = (off + bytes + 255) & ~(size_t)255;
    return p;
  };
  unsigned short* WtP0   = (unsigned short*)take((size_t)768 * 512 * 2);
  unsigned short* Wtew20 = (unsigned short*)take((size_t)256 * 256 * 2);
  unsigned short* Wtwme0 = (unsigned short*)take((size_t)256 * 256 * 2);
  unsigned short* Wtnw1  = (unsigned short*)take((size_t)256 * 768 * 2);
  unsigned short* Wtnw2  = (unsigned short*)take((size_t)256 * 256 * 2);
  unsigned short* WtP1   = (unsigned short*)take((size_t)512 * 256 * 2);
  unsigned short* Wtw1c1 = (unsigned short*)take((size_t)256 * 256 * 2);
  unsigned short* Wtew21 = (unsigned short*)take((size_t)256 * 256 * 2);
  unsigned short* Wtpw1  = (unsigned short*)take((size_t)256 * 256 * 2);
  // Region A: P0 (f32 [10000][768]) lives here during layer 0; after edge_pass0
  // it is dead and NH (offset 0, 10.24MB) then P1 (offset 10.24MB, 20.48MB) reuse it.
  float* P0  = (float*)take((size_t)N_NODES * 768 * 4);
  float* NH  = P0;
  float* P1  = P0 + (size_t)N_NODES * 256;
  float* S   = (float*)take((size_t)N_NODES * 256 * 4);
  float* X1  = S;    // X1 computed after S is dead
  float* CNT = (float*)take((size_t)N_NODES * 4);
  unsigned short* EA1 = (unsigned short*)take((size_t)N_EDGES * 256 * 2);
  (void)ws_size; (void)in_sizes; (void)n_in; (void)out_size;

  TJobs jobs;
  auto J = [&](int idx, const float* in, unsigned short* outp, int K, int N, int row0, int ld){
    jobs.j[idx].in = in; jobs.j[idx].out = outp; jobs.j[idx].K = K;
    jobs.j[idx].N = N; jobs.j[idx].row0 = row0; jobs.j[idx].ld = ld;
  };
  J(0,  e_w1_0, WtP0,            512, 256,   0, 256);  // pA0
  J(1,  e_w1_0, WtP0 + 256*512,  512, 256, 512, 256);  // pB0
  J(2,  n_wm_0, WtP0 + 512*512,  512, 256,   0, 256);  // pM0
  J(3,  e_w2_0, Wtew20, 256, 256,   0, 256);
  J(4,  n_wm_0, Wtwme0, 256, 256, 512, 256);
  J(5,  n_w1_0, Wtnw1,  768, 256,   0, 256);
  J(6,  n_w2_0, Wtnw2,  256, 256,   0, 256);
  J(7,  e_w1_1, WtP1,            256, 256,   0, 256);  // pA1
  J(8,  e_w1_1, WtP1 + 256*256,  256, 256, 256, 256);  // pB1
  J(9,  e_w1_1, Wtw1c1, 256, 256, 512, 256);
  J(10, e_w2_1, Wtew21, 256, 256,   0, 256);
  J(11, p_w1,   Wtpw1,  256, 256,   0, 256);
  prep_weights<<<dim3(768, 12), 256, 0, stream>>>(jobs);

  hipMemsetAsync(S, 0, (size_t)N_NODES * 256 * 4, stream);
  hipMemsetAsync(CNT, 0, (size_t)N_NODES * 4, stream);

  const int NT = (N_NODES + 63) / 64;   // 157
  // P0 = x @ [pA0|pB0|pM0]
  gemm_nodes<<<dim3(NT, 3), 256, 0, stream>>>(x, 512, nullptr, 0, WtP0, nullptr, P0, 768, 0);
  edge_pass0<<<N_EDGES / 64, 256, 0, stream>>>(ei, eattr, P0, e_w1_0 + 1024 * 256, e_b1_0,
                                               Wtew20, e_b2_0, Wtwme0, n_bm_0, EA1, S, CNT);
  norm_s<<<(N_NODES * 256) / 256, 256, 0, stream>>>(S, CNT);
  // NH = relu([x|S] @ n_w1_0 + b)     (NH overlays dead P0)
  gemm_nodes<<<dim3(NT, 1), 256, 0, stream>>>(x, 512, S, 256, Wtnw1, n_b1_0, NH, 256, 1);
  // X1 = NH @ n_w2_0 + b (+x residual? dims differ: 512 vs 256 -> no residual)  (X1 overlays dead S)
  gemm_nodes<<<dim3(NT, 1), 256, 0, stream>>>(NH, 256, nullptr, 0, Wtnw2, n_b2_0, X1, 256, 0);
  // P1 = X1 @ [pA1|pB1]               (P1 overlays Region A after NH is consumed)
  gemm_nodes<<<dim3(NT, 2), 256, 0, stream>>>(X1, 256, nullptr, 0, WtP1, nullptr, P1, 512, 0);
  edge_pass1<<<N_EDGES / 64, 256, 0, stream>>>(ei, EA1, P1, e_b1_1, Wtw1c1, Wtew21, e_b2_1,
                                               Wtpw1, p_b1, p_w2, p_b2, out);
}

// Round 3
// 990.814 us; speedup vs baseline: 1.1181x; 1.1181x over previous
//
#include <hip/hip_runtime.h>
#include <stdint.h>

#define N_NODES 10000
#define N_EDGES 160000

typedef __attribute__((ext_vector_type(8))) short bf16x8;
typedef __attribute__((ext_vector_type(4))) float f32x4;
typedef __attribute__((ext_vector_type(4))) unsigned short ushort4v;

__device__ __forceinline__ unsigned short f2bf(float f){
  union { float f; unsigned u; } v; v.f = f;
  unsigned u = v.u;
  u += 0x7fffu + ((u >> 16) & 1u);       // round-to-nearest-even
  return (unsigned short)(u >> 16);
}
__device__ __forceinline__ float bf2f(unsigned short h){
  union { unsigned u; float f; } v; v.u = ((unsigned)h) << 16; return v.f;
}
__device__ __forceinline__ int clampi(int v){
  return v < 0 ? 0 : (v >= N_NODES ? N_NODES - 1 : v);
}

// ---------------- weight transpose + bf16 convert ----------------
struct TJob { const float* in; unsigned short* out; int K; int N; int row0; int ld; };
struct TJobs { TJob j[12]; };

__global__ __launch_bounds__(256) void prep_weights(TJobs jobs){
  TJob jb = jobs.j[blockIdx.y];
  int total = jb.K * jb.N;
  int i = blockIdx.x * 256 + threadIdx.x;
  if (i >= total) return;
  int n = i / jb.K;
  int k = i - n * jb.K;
  jb.out[(size_t)n * jb.K + k] = f2bf(jb.in[(size_t)(jb.row0 + k) * jb.ld + n]);
}

// ---- 4x4-fragment MFMA block over a 64x(256-chunk) LDS tile --------------
// A: LDS [64 rows][256 bf16], XOR-swizzled: byte = row*512 + (colbyte ^ ((row&7)<<4))
// Wt: row-major [outCols][wstride] bf16 (pre-transposed weights). Wave w
// computes cols w*64..w*64+63.
__device__ __forceinline__ void mfma_tiles(const unsigned short* __restrict__ A,
                                           const unsigned short* __restrict__ Wt,
                                           int wstride, int l, int w, f32x4 acc[4][4])
{
  #pragma unroll
  for (int ks = 0; ks < 8; ks++){
    const int kb = ks * 64 + ((l >> 4) << 4);     // byte offset of this lane's 8 bf16
    bf16x8 a[4];
    #pragma unroll
    for (int mi = 0; mi < 4; mi++){
      const int row = mi * 16 + (l & 15);
      a[mi] = *(const bf16x8*)((const char*)A + row * 512 + (kb ^ ((row & 7) << 4)));
    }
    #pragma unroll
    for (int ni = 0; ni < 4; ni++){
      const unsigned short* bp = Wt + (size_t)((w * 4 + ni) * 16 + (l & 15)) * wstride;
      bf16x8 b = *(const bf16x8*)((const char*)bp + kb);
      #pragma unroll
      for (int mi = 0; mi < 4; mi++)
        acc[mi][ni] = __builtin_amdgcn_mfma_f32_16x16x32_bf16(a[mi], b, acc[mi][ni], 0, 0, 0);
    }
  }
}
__device__ __forceinline__ void zero_acc(f32x4 acc[4][4]){
  #pragma unroll
  for (int mi = 0; mi < 4; mi++)
    #pragma unroll
    for (int ni = 0; ni < 4; ni++)
      acc[mi][ni] = (f32x4){0.f, 0.f, 0.f, 0.f};
}

// ---------------- generic node GEMM: C = act(A1|A2 @ Wt + bias) ----------------
__global__ __launch_bounds__(256) void gemm_nodes(
    const float* __restrict__ A1, int K1,
    const float* __restrict__ A2, int K2,
    const unsigned short* __restrict__ Wt,   // [NcTot][Ktot]
    const float* __restrict__ bias,
    void* __restrict__ Cout, int NcTot, int relu, int out_bf16)
{
  __shared__ __align__(16) unsigned short As[64 * 256];
  const int t = threadIdx.x, w = t >> 6, l = t & 63;
  const int rowBase = blockIdx.x * 64;
  const int bc = blockIdx.y;
  const int Ktot = K1 + K2;
  f32x4 acc[4][4] = {};
  for (int kc = 0; kc < Ktot; kc += 256){
    __syncthreads();
    {
      const int r = t >> 2, q = t & 3;
      int rg = rowBase + r; if (rg >= N_NODES) rg = N_NODES - 1;
      const float* src = (kc < K1) ? (A1 + (size_t)rg * K1 + kc)
                                   : (A2 + (size_t)rg * K2 + (kc - K1));
      #pragma unroll
      for (int u = 0; u < 16; u++){
        const int cb = q * 128 + u * 8;
        f32x4 v = *(const f32x4*)(src + q * 64 + u * 4);
        ushort4v h; h[0] = f2bf(v[0]); h[1] = f2bf(v[1]); h[2] = f2bf(v[2]); h[3] = f2bf(v[3]);
        *(ushort4v*)((char*)As + r * 512 + (cb ^ ((r & 7) << 4))) = h;
      }
    }
    __syncthreads();
    mfma_tiles(As, Wt + (size_t)(bc * 256) * Ktot + kc, Ktot, l, w, acc);
  }
  #pragma unroll
  for (int mi = 0; mi < 4; mi++)
  #pragma unroll
  for (int ni = 0; ni < 4; ni++){
    const int colAbs = bc * 256 + (w * 4 + ni) * 16 + (l & 15);
    const float bv = bias ? bias[colAbs] : 0.f;
    #pragma unroll
    for (int r = 0; r < 4; r++){
      const int rowg = rowBase + mi * 16 + (l >> 4) * 4 + r;
      if (rowg < N_NODES){
        float v = acc[mi][ni][r] + bv;
        if (relu) v = fmaxf(v, 0.f);
        if (out_bf16) ((unsigned short*)Cout)[(size_t)rowg * NcTot + colAbs] = f2bf(v);
        else          ((float*)Cout)[(size_t)rowg * NcTot + colAbs] = v;
      }
    }
  }
}

// ---------------- layer-0 fused edge pass (single 32KB LDS buffer) ----------
// EH = relu(pA0[src] + pB0[dst] + ea@W1c + b1)   -> B
// ea1 = EH @ e_w2_0 + b2          (acc regs; after sync, written back into B)
// msg = relu(ea1 @ Wm_e + pM0[src] + bm); atomic-add into S[dst]
__global__ __launch_bounds__(256, 3) void edge_pass0(
    const int* __restrict__ ei,
    const float* __restrict__ ea,
    const unsigned short* __restrict__ P0h,  // [N][768] bf16 = pA0|pB0|pM0
    const float* __restrict__ W1c,           // [6][256] f32
    const float* __restrict__ b1,
    const unsigned short* __restrict__ Wt_ew2,
    const float* __restrict__ b2,
    const unsigned short* __restrict__ Wt_wme,
    const float* __restrict__ bm,
    unsigned short* __restrict__ EA1,
    float* __restrict__ S,
    float* __restrict__ CNT)
{
  __shared__ __align__(16) unsigned short B[64 * 256];
  const int t = threadIdx.x, w = t >> 6, l = t & 63;
  const int e0 = blockIdx.x * 64;
  if (t < 64){
    atomicAdd(&CNT[clampi(ei[N_EDGES + e0 + t])], 1.0f);
  }
  // phase E: EH -> B
  {
    const int r = t >> 2, q = t & 3;
    const int e = e0 + r;
    const int sv = clampi(ei[e]);
    const int dv = clampi(ei[N_EDGES + e]);
    const unsigned short* pa = P0h + (size_t)sv * 768;
    const unsigned short* pb = P0h + (size_t)dv * 768 + 256;
    float eav[6];
    #pragma unroll
    for (int k = 0; k < 6; k++) eav[k] = ea[(size_t)e * 6 + k];
    #pragma unroll
    for (int u = 0; u < 8; u++){
      const int c = q * 64 + u * 8;
      bf16x8 va = *(const bf16x8*)(pa + c);
      bf16x8 vb = *(const bf16x8*)(pb + c);
      bf16x8 h;
      #pragma unroll
      for (int j = 0; j < 8; j++){
        float v = bf2f((unsigned short)va[j]) + bf2f((unsigned short)vb[j]) + b1[c + j];
        #pragma unroll
        for (int k = 0; k < 6; k++) v += eav[k] * W1c[k * 256 + c + j];
        h[j] = (short)f2bf(fmaxf(v, 0.f));
      }
      *(bf16x8*)((char*)B + r * 512 + ((2 * c) ^ ((r & 7) << 4))) = h;
    }
  }
  __syncthreads();
  // GEMM1: ea1 in acc
  f32x4 acc[4][4];
  zero_acc(acc);
  mfma_tiles(B, Wt_ew2, 256, l, w, acc);
  __syncthreads();                     // all reads of EH done
  // write ea1 back into B (same swizzled layout)
  #pragma unroll
  for (int mi = 0; mi < 4; mi++)
  #pragma unroll
  for (int ni = 0; ni < 4; ni++){
    const int col = (w * 4 + ni) * 16 + (l & 15);
    const float bb = b2[col];
    #pragma unroll
    for (int r = 0; r < 4; r++){
      const int row = mi * 16 + (l >> 4) * 4 + r;
      *(unsigned short*)((char*)B + row * 512 + ((2 * col) ^ ((row & 7) << 4)))
          = f2bf(acc[mi][ni][r] + bb);
    }
  }
  __syncthreads();
  // coalesced copy B -> EA1 (global)
  {
    const int r = t >> 2, q = t & 3;
    char* gdst = (char*)EA1 + (size_t)(e0 + r) * 512 + q * 128;
    #pragma unroll
    for (int u = 0; u < 8; u++){
      const int cb = q * 128 + u * 16;
      *(bf16x8*)(gdst + u * 16) =
        *(const bf16x8*)((const char*)B + r * 512 + (cb ^ ((r & 7) << 4)));
    }
  }
  // GEMM2: msg + atomic scatter (reads B concurrently with the copy above)
  zero_acc(acc);
  mfma_tiles(B, Wt_wme, 256, l, w, acc);
  #pragma unroll
  for (int mi = 0; mi < 4; mi++)
  #pragma unroll
  for (int ni = 0; ni < 4; ni++){
    const int col = (w * 4 + ni) * 16 + (l & 15);
    const float bb = bm[col];
    #pragma unroll
    for (int r = 0; r < 4; r++){
      const int row = mi * 16 + (l >> 4) * 4 + r;
      const int e = e0 + row;
      const int sv = clampi(ei[e]);
      const int dv = clampi(ei[N_EDGES + e]);
      float v = acc[mi][ni][r] + bb + bf2f(P0h[(size_t)sv * 768 + 512 + col]);
      v = fmaxf(v, 0.f);
      atomicAdd(&S[(size_t)dv * 256 + col], v);
    }
  }
}

// ---------------- mean normalize ----------------
__global__ __launch_bounds__(256) void norm_s(float* __restrict__ S, const float* __restrict__ CNT){
  const int i = blockIdx.x * 256 + threadIdx.x;
  const float c = fmaxf(CNT[i >> 8], 1.f);
  S[i] = S[i] / c;
}

// ---------------- layer-1 fused edge pass + predictor head (single buffer) --
// eh1 = relu(ea1 @ W1c1 + pA1[src] + pB1[dst] + b1)
// ea2 = eh1 @ e_w2_1 + b2 + ea1
// out = relu(ea2 @ p_w1 + p_b1) . p_w2 + p_b2
__global__ __launch_bounds__(256, 3) void edge_pass1(
    const int* __restrict__ ei,
    const unsigned short* __restrict__ EA1,
    const unsigned short* __restrict__ P1h,  // [N][512] bf16 = pA1|pB1
    const float* __restrict__ b1,            // e_b1_1
    const unsigned short* __restrict__ Wt_w1c,
    const unsigned short* __restrict__ Wt_ew2,
    const float* __restrict__ b2,            // e_b2_1
    const unsigned short* __restrict__ Wt_pw1,
    const float* __restrict__ pb1,
    const float* __restrict__ pw2,
    const float* __restrict__ pb2,
    float* __restrict__ out)
{
  __shared__ __align__(16) unsigned short B[64 * 256];
  __shared__ float partial[256];
  const int t = threadIdx.x, w = t >> 6, l = t & 63;
  const int e0 = blockIdx.x * 64;
  // load ea1 tile -> B (swizzled)
  {
    const int r = t >> 2, q = t & 3;
    const char* gsrc = (const char*)EA1 + (size_t)(e0 + r) * 512 + q * 128;
    #pragma unroll
    for (int u = 0; u < 8; u++){
      const int cb = q * 128 + u * 16;
      *(bf16x8*)((char*)B + r * 512 + (cb ^ ((r & 7) << 4))) = *(const bf16x8*)(gsrc + u * 16);
    }
  }
  __syncthreads();
  // GEMM_a: eh1 in acc
  f32x4 acc[4][4];
  zero_acc(acc);
  mfma_tiles(B, Wt_w1c, 256, l, w, acc);
  // residual: read this wave's C-quadrant of ea1 from B before overwrite
  unsigned res[4][4][2];
  #pragma unroll
  for (int mi = 0; mi < 4; mi++)
  #pragma unroll
  for (int ni = 0; ni < 4; ni++){
    const int col = (w * 4 + ni) * 16 + (l & 15);
    #pragma unroll
    for (int rp = 0; rp < 2; rp++){
      const int row0 = mi * 16 + (l >> 4) * 4 + rp * 2;
      unsigned a0 = *(const unsigned short*)((const char*)B + row0 * 512 + ((2 * col) ^ ((row0 & 7) << 4)));
      const int row1 = row0 + 1;
      unsigned a1 = *(const unsigned short*)((const char*)B + row1 * 512 + ((2 * col) ^ ((row1 & 7) << 4)));
      res[mi][ni][rp] = a0 | (a1 << 16);
    }
  }
  __syncthreads();
  // write eh1 into B (with P1 gathers + relu)
  #pragma unroll
  for (int mi = 0; mi < 4; mi++)
  #pragma unroll
  for (int ni = 0; ni < 4; ni++){
    const int col = (w * 4 + ni) * 16 + (l & 15);
    const float bb = b1[col];
    #pragma unroll
    for (int r = 0; r < 4; r++){
      const int row = mi * 16 + (l >> 4) * 4 + r;
      const int e = e0 + row;
      const int sv = clampi(ei[e]);
      const int dv = clampi(ei[N_EDGES + e]);
      float v = acc[mi][ni][r] + bb + bf2f(P1h[(size_t)sv * 512 + col])
              + bf2f(P1h[(size_t)dv * 512 + 256 + col]);
      *(unsigned short*)((char*)B + row * 512 + ((2 * col) ^ ((row & 7) << 4)))
          = f2bf(fmaxf(v, 0.f));
    }
  }
  __syncthreads();
  // GEMM_b: ea2 = eh1 @ W2 + b2 + ea1
  zero_acc(acc);
  mfma_tiles(B, Wt_ew2, 256, l, w, acc);
  __syncthreads();
  #pragma unroll
  for (int mi = 0; mi < 4; mi++)
  #pragma unroll
  for (int ni = 0; ni < 4; ni++){
    const int col = (w * 4 + ni) * 16 + (l & 15);
    const float bb = b2[col];
    #pragma unroll
    for (int rp = 0; rp < 2; rp++){
      const unsigned rr = res[mi][ni][rp];
      const int row0 = mi * 16 + (l >> 4) * 4 + rp * 2;
      const int row1 = row0 + 1;
      float v0 = acc[mi][ni][rp * 2 + 0] + bb + bf2f((unsigned short)(rr & 0xffff));
      float v1 = acc[mi][ni][rp * 2 + 1] + bb + bf2f((unsigned short)(rr >> 16));
      *(unsigned short*)((char*)B + row0 * 512 + ((2 * col) ^ ((row0 & 7) << 4))) = f2bf(v0);
      *(unsigned short*)((char*)B + row1 * 512 + ((2 * col) ^ ((row1 & 7) << 4))) = f2bf(v1);
    }
  }
  __syncthreads();
  // GEMM_c: h = relu(ea2 @ p_w1 + pb1); rowsum(h * pw2)
  zero_acc(acc);
  mfma_tiles(B, Wt_pw1, 256, l, w, acc);
  {
    float rs[4][4];
    #pragma unroll
    for (int mi = 0; mi < 4; mi++)
      #pragma unroll
      for (int r = 0; r < 4; r++) rs[mi][r] = 0.f;
    #pragma unroll
    for (int mi = 0; mi < 4; mi++)
    #pragma unroll
    for (int ni = 0; ni < 4; ni++){
      const int col = (w * 4 + ni) * 16 + (l & 15);
      const float pb = pb1[col];
      const float pw = pw2[col];
      #pragma unroll
      for (int r = 0; r < 4; r++)
        rs[mi][r] += fmaxf(acc[mi][ni][r] + pb, 0.f) * pw;
    }
    #pragma unroll
    for (int off = 1; off < 16; off <<= 1){
      #pragma unroll
      for (int mi = 0; mi < 4; mi++)
        #pragma unroll
        for (int r = 0; r < 4; r++)
          rs[mi][r] += __shfl_xor(rs[mi][r], off);
    }
    if ((l & 15) == 0){
      #pragma unroll
      for (int mi = 0; mi < 4; mi++)
        #pragma unroll
        for (int r = 0; r < 4; r++)
          partial[w * 64 + mi * 16 + (l >> 4) * 4 + r] = rs[mi][r];
    }
  }
  __syncthreads();
  if (t < 64)
    out[e0 + t] = partial[t] + partial[64 + t] + partial[128 + t] + partial[192 + t] + pb2[0];
}

// ---------------- host ----------------
extern "C" void kernel_launch(void* const* d_in, const int* in_sizes, int n_in,
                              void* d_out, int out_size, void* d_ws, size_t ws_size,
                              hipStream_t stream)
{
  const float* x      = (const float*)d_in[0];
  const int* ei       = (const int*)d_in[1];        // int32 per harness contract
  const float* eattr  = (const float*)d_in[2];
  const float* e_w1_0 = (const float*)d_in[3];
  const float* e_b1_0 = (const float*)d_in[4];
  const float* e_w2_0 = (const float*)d_in[5];
  const float* e_b2_0 = (const float*)d_in[6];
  const float* n_wm_0 = (const float*)d_in[7];
  const float* n_bm_0 = (const float*)d_in[8];
  const float* n_w1_0 = (const float*)d_in[9];
  const float* n_b1_0 = (const float*)d_in[10];
  const float* n_w2_0 = (const float*)d_in[11];
  const float* n_b2_0 = (const float*)d_in[12];
  const float* e_w1_1 = (const float*)d_in[13];
  const float* e_b1_1 = (const float*)d_in[14];
  const float* e_w2_1 = (const float*)d_in[15];
  const float* e_b2_1 = (const float*)d_in[16];
  // d_in[17..22] (layer-1 node model) are dead code for the output
  const float* p_w1   = (const float*)d_in[23];
  const float* p_b1   = (const float*)d_in[24];
  const float* p_w2   = (const float*)d_in[25];
  const float* p_b2   = (const float*)d_in[26];
  float* out = (float*)d_out;

  char* base = (char*)d_ws;
  size_t off = 0;
  auto take = [&](size_t bytes)->void*{
    void* p = base + off;
    off = (off + bytes + 255) & ~(size_t)255;
    return p;
  };
  unsigned short* WtP0   = (unsigned short*)take((size_t)768 * 512 * 2);
  unsigned short* Wtew20 = (unsigned short*)take((size_t)256 * 256 * 2);
  unsigned short* Wtwme0 = (unsigned short*)take((size_t)256 * 256 * 2);
  unsigned short* Wtnw1  = (unsigned short*)take((size_t)256 * 768 * 2);
  unsigned short* Wtnw2  = (unsigned short*)take((size_t)256 * 256 * 2);
  unsigned short* WtP1   = (unsigned short*)take((size_t)512 * 256 * 2);
  unsigned short* Wtw1c1 = (unsigned short*)take((size_t)256 * 256 * 2);
  unsigned short* Wtew21 = (unsigned short*)take((size_t)256 * 256 * 2);
  unsigned short* Wtpw1  = (unsigned short*)take((size_t)256 * 256 * 2);
  // Region A (15.36MB): P0h (bf16 [10000][768]) lives here during layer 0.
  // After edge_pass0 it is dead: NH (f32, 10.24MB) overlays it, then P1h
  // (bf16, 10.24MB) overlays again after NH is consumed.
  char* regionA = (char*)take((size_t)N_NODES * 768 * 2);
  unsigned short* P0h = (unsigned short*)regionA;
  float* NH           = (float*)regionA;          // valid: NH is 10.24MB < 15.36MB
  unsigned short* P1h = (unsigned short*)regionA; // written after NH is dead
  float* S   = (float*)take((size_t)N_NODES * 256 * 4);
  float* X1  = S;    // X1 computed after S is dead
  float* CNT = (float*)take((size_t)N_NODES * 4);
  unsigned short* EA1 = (unsigned short*)take((size_t)N_EDGES * 256 * 2);
  (void)ws_size; (void)in_sizes; (void)n_in; (void)out_size;

  TJobs jobs;
  auto J = [&](int idx, const float* in, unsigned short* outp, int K, int N, int row0, int ld){
    jobs.j[idx].in = in; jobs.j[idx].out = outp; jobs.j[idx].K = K;
    jobs.j[idx].N = N; jobs.j[idx].row0 = row0; jobs.j[idx].ld = ld;
  };
  J(0,  e_w1_0, WtP0,            512, 256,   0, 256);  // pA0
  J(1,  e_w1_0, WtP0 + 256*512,  512, 256, 512, 256);  // pB0
  J(2,  n_wm_0, WtP0 + 512*512,  512, 256,   0, 256);  // pM0
  J(3,  e_w2_0, Wtew20, 256, 256,   0, 256);
  J(4,  n_wm_0, Wtwme0, 256, 256, 512, 256);
  J(5,  n_w1_0, Wtnw1,  768, 256,   0, 256);
  J(6,  n_w2_0, Wtnw2,  256, 256,   0, 256);
  J(7,  e_w1_1, WtP1,            256, 256,   0, 256);  // pA1
  J(8,  e_w1_1, WtP1 + 256*256,  256, 256, 256, 256);  // pB1
  J(9,  e_w1_1, Wtw1c1, 256, 256, 512, 256);
  J(10, e_w2_1, Wtew21, 256, 256,   0, 256);
  J(11, p_w1,   Wtpw1,  256, 256,   0, 256);
  prep_weights<<<dim3(768, 12), 256, 0, stream>>>(jobs);

  hipMemsetAsync(S, 0, (size_t)N_NODES * 256 * 4, stream);
  hipMemsetAsync(CNT, 0, (size_t)N_NODES * 4, stream);

  const int NT = (N_NODES + 63) / 64;   // 157
  // P0h = bf16( x @ [pA0|pB0|pM0] )
  gemm_nodes<<<dim3(NT, 3), 256, 0, stream>>>(x, 512, nullptr, 0, WtP0, nullptr, P0h, 768, 0, 1);
  edge_pass0<<<N_EDGES / 64, 256, 0, stream>>>(ei, eattr, P0h, e_w1_0 + 1024 * 256, e_b1_0,
                                               Wtew20, e_b2_0, Wtwme0, n_bm_0, EA1, S, CNT);
  norm_s<<<(N_NODES * 256) / 256, 256, 0, stream>>>(S, CNT);
  // NH = relu([x|S] @ n_w1_0 + b)     (NH overlays dead P0h)
  gemm_nodes<<<dim3(NT, 1), 256, 0, stream>>>(x, 512, S, 256, Wtnw1, n_b1_0, NH, 256, 1, 0);
  // X1 = NH @ n_w2_0 + b              (X1 overlays dead S)
  gemm_nodes<<<dim3(NT, 1), 256, 0, stream>>>(NH, 256, nullptr, 0, Wtnw2, n_b2_0, X1, 256, 0, 0);
  // P1h = bf16( X1 @ [pA1|pB1] )      (overlays region A after NH is consumed)
  gemm_nodes<<<dim3(NT, 2), 256, 0, stream>>>(X1, 256, nullptr, 0, WtP1, nullptr, P1h, 512, 0, 1);
  edge_pass1<<<N_EDGES / 64, 256, 0, stream>>>(ei, EA1, P1h, e_b1_1, Wtw1c1, Wtew21, e_b2_1,
                                               Wtpw1, p_b1, p_w2, p_b2, out);
}

// Round 4
// 936.966 us; speedup vs baseline: 1.1824x; 1.0575x over previous
//
#include <hip/hip_runtime.h>
#include <stdint.h>

#define N_NODES 10000
#define N_EDGES 160000
#define EROWS 32

typedef __attribute__((ext_vector_type(8))) short bf16x8;
typedef __attribute__((ext_vector_type(4))) float f32x4;
typedef __attribute__((ext_vector_type(4))) unsigned short ushort4v;

__device__ __forceinline__ unsigned short f2bf(float f){
  union { float f; unsigned u; } v; v.f = f;
  unsigned u = v.u;
  u += 0x7fffu + ((u >> 16) & 1u);       // round-to-nearest-even
  return (unsigned short)(u >> 16);
}
__device__ __forceinline__ float bf2f(unsigned short h){
  union { unsigned u; float f; } v; v.u = ((unsigned)h) << 16; return v.f;
}
__device__ __forceinline__ int clampi(int v){
  return v < 0 ? 0 : (v >= N_NODES ? N_NODES - 1 : v);
}

// ---------------- weight transpose + bf16 convert ----------------
struct TJob { const float* in; unsigned short* out; int K; int N; int row0; int ld; };
struct TJobs { TJob j[12]; };

__global__ __launch_bounds__(256) void prep_weights(TJobs jobs){
  TJob jb = jobs.j[blockIdx.y];
  int total = jb.K * jb.N;
  int i = blockIdx.x * 256 + threadIdx.x;
  if (i >= total) return;
  int n = i / jb.K;
  int k = i - n * jb.K;
  jb.out[(size_t)n * jb.K + k] = f2bf(jb.in[(size_t)(jb.row0 + k) * jb.ld + n]);
}

// ---- MFMA over a [ROWS][256] bf16 LDS tile, per-wave 32x64 output ----------
// A: LDS XOR-swizzled: byte = row*512 + (colbyte ^ ((row&7)<<4))
// Wt: row-major [outCols][wstride] bf16. Wave w computes cols w*64..w*64+63.
__device__ __forceinline__ void mfma_tiles32(const unsigned short* __restrict__ A,
                                             const unsigned short* __restrict__ Wt,
                                             int wstride, int l, int w, f32x4 acc[2][4])
{
  #pragma unroll
  for (int ks = 0; ks < 8; ks++){
    const int kb = ks * 64 + ((l >> 4) << 4);     // byte offset of this lane's 8 bf16
    bf16x8 a[2];
    #pragma unroll
    for (int mi = 0; mi < 2; mi++){
      const int row = mi * 16 + (l & 15);
      a[mi] = *(const bf16x8*)((const char*)A + row * 512 + (kb ^ ((row & 7) << 4)));
    }
    #pragma unroll
    for (int ni = 0; ni < 4; ni++){
      const unsigned short* bp = Wt + (size_t)((w * 4 + ni) * 16 + (l & 15)) * wstride;
      bf16x8 b = *(const bf16x8*)((const char*)bp + kb);
      #pragma unroll
      for (int mi = 0; mi < 2; mi++)
        acc[mi][ni] = __builtin_amdgcn_mfma_f32_16x16x32_bf16(a[mi], b, acc[mi][ni], 0, 0, 0);
    }
  }
}
__device__ __forceinline__ void zero_acc32(f32x4 acc[2][4]){
  #pragma unroll
  for (int mi = 0; mi < 2; mi++)
    #pragma unroll
    for (int ni = 0; ni < 4; ni++)
      acc[mi][ni] = (f32x4){0.f, 0.f, 0.f, 0.f};
}

// ---- 64-row variant for node GEMMs (few blocks, perf non-critical) ---------
__device__ __forceinline__ void mfma_tiles64(const unsigned short* __restrict__ A,
                                             const unsigned short* __restrict__ Wt,
                                             int wstride, int l, int w, f32x4 acc[4][4])
{
  #pragma unroll
  for (int ks = 0; ks < 8; ks++){
    const int kb = ks * 64 + ((l >> 4) << 4);
    bf16x8 a[4];
    #pragma unroll
    for (int mi = 0; mi < 4; mi++){
      const int row = mi * 16 + (l & 15);
      a[mi] = *(const bf16x8*)((const char*)A + row * 512 + (kb ^ ((row & 7) << 4)));
    }
    #pragma unroll
    for (int ni = 0; ni < 4; ni++){
      const unsigned short* bp = Wt + (size_t)((w * 4 + ni) * 16 + (l & 15)) * wstride;
      bf16x8 b = *(const bf16x8*)((const char*)bp + kb);
      #pragma unroll
      for (int mi = 0; mi < 4; mi++)
        acc[mi][ni] = __builtin_amdgcn_mfma_f32_16x16x32_bf16(a[mi], b, acc[mi][ni], 0, 0, 0);
    }
  }
}

// ---------------- generic node GEMM: C = act([A1|A2/cnt] @ Wt + bias) -------
__global__ __launch_bounds__(256) void gemm_nodes(
    const float* __restrict__ A1, int K1,
    const float* __restrict__ A2, int K2,
    const unsigned short* __restrict__ Wt,   // [NcTot][Ktot]
    const float* __restrict__ bias,
    void* __restrict__ Cout, int NcTot, int relu, int out_bf16,
    const float* __restrict__ cnt)           // if set: divide A2 rows by max(cnt,1)
{
  __shared__ __align__(16) unsigned short As[64 * 256];
  const int t = threadIdx.x, w = t >> 6, l = t & 63;
  const int rowBase = blockIdx.x * 64;
  const int bc = blockIdx.y;
  const int Ktot = K1 + K2;
  f32x4 acc[4][4] = {};
  for (int kc = 0; kc < Ktot; kc += 256){
    __syncthreads();
    {
      const int r = t >> 2, q = t & 3;
      int rg = rowBase + r; if (rg >= N_NODES) rg = N_NODES - 1;
      const int inA2 = (kc >= K1);
      const float* src = !inA2 ? (A1 + (size_t)rg * K1 + kc)
                               : (A2 + (size_t)rg * K2 + (kc - K1));
      const float inv = (cnt && inA2) ? (1.f / fmaxf(cnt[rg], 1.f)) : 1.f;
      #pragma unroll
      for (int u = 0; u < 16; u++){
        const int cb = q * 128 + u * 8;
        f32x4 v = *(const f32x4*)(src + q * 64 + u * 4);
        ushort4v h;
        h[0] = f2bf(v[0] * inv); h[1] = f2bf(v[1] * inv);
        h[2] = f2bf(v[2] * inv); h[3] = f2bf(v[3] * inv);
        *(ushort4v*)((char*)As + r * 512 + (cb ^ ((r & 7) << 4))) = h;
      }
    }
    __syncthreads();
    mfma_tiles64(As, Wt + (size_t)(bc * 256) * Ktot + kc, Ktot, l, w, acc);
  }
  #pragma unroll
  for (int mi = 0; mi < 4; mi++)
  #pragma unroll
  for (int ni = 0; ni < 4; ni++){
    const int colAbs = bc * 256 + (w * 4 + ni) * 16 + (l & 15);
    const float bv = bias ? bias[colAbs] : 0.f;
    #pragma unroll
    for (int r = 0; r < 4; r++){
      const int rowg = rowBase + mi * 16 + (l >> 4) * 4 + r;
      if (rowg < N_NODES){
        float v = acc[mi][ni][r] + bv;
        if (relu) v = fmaxf(v, 0.f);
        if (out_bf16) ((unsigned short*)Cout)[(size_t)rowg * NcTot + colAbs] = f2bf(v);
        else          ((float*)Cout)[(size_t)rowg * NcTot + colAbs] = v;
      }
    }
  }
}

// ---------------- layer-0 fused edge pass (32-edge tile, 16KB LDS) ----------
// EH = relu(pA0[src] + pB0[dst] + ea@W1c + b1)   -> B
// ea1 = EH @ e_w2_0 + b2          (acc; written back into B, copied to EA1)
// msg = relu(ea1 @ Wm_e + pM0[src] + bm); atomic-add into S[dst]
__global__ __launch_bounds__(256, 4) void edge_pass0(
    const int* __restrict__ ei,
    const float* __restrict__ ea,
    const unsigned short* __restrict__ P0h,  // [N][768] bf16 = pA0|pB0|pM0
    const float* __restrict__ W1c,           // [6][256] f32
    const float* __restrict__ b1,
    const unsigned short* __restrict__ Wt_ew2,
    const float* __restrict__ b2,
    const unsigned short* __restrict__ Wt_wme,
    const float* __restrict__ bm,
    unsigned short* __restrict__ EA1,
    float* __restrict__ S,
    float* __restrict__ CNT)
{
  __shared__ __align__(16) unsigned short B[EROWS * 256];
  const int t = threadIdx.x, w = t >> 6, l = t & 63;
  const int e0 = blockIdx.x * EROWS;
  if (t < EROWS){
    atomicAdd(&CNT[clampi(ei[N_EDGES + e0 + t])], 1.0f);
  }
  // phase E: EH -> B   (8 threads per edge row, 32 cols each)
  {
    const int r = t >> 3, q = t & 7;
    const int e = e0 + r;
    const int sv = clampi(ei[e]);
    const int dv = clampi(ei[N_EDGES + e]);
    const unsigned short* pa = P0h + (size_t)sv * 768;
    const unsigned short* pb = P0h + (size_t)dv * 768 + 256;
    float eav[6];
    #pragma unroll
    for (int k = 0; k < 6; k++) eav[k] = ea[(size_t)e * 6 + k];
    #pragma unroll
    for (int u = 0; u < 4; u++){
      const int c = q * 32 + u * 8;
      bf16x8 va = *(const bf16x8*)(pa + c);
      bf16x8 vb = *(const bf16x8*)(pb + c);
      bf16x8 h;
      #pragma unroll
      for (int j = 0; j < 8; j++){
        float v = bf2f((unsigned short)va[j]) + bf2f((unsigned short)vb[j]) + b1[c + j];
        #pragma unroll
        for (int k = 0; k < 6; k++) v += eav[k] * W1c[k * 256 + c + j];
        h[j] = (short)f2bf(fmaxf(v, 0.f));
      }
      *(bf16x8*)((char*)B + r * 512 + ((2 * c) ^ ((r & 7) << 4))) = h;
    }
  }
  __syncthreads();
  // GEMM1: ea1 in acc
  f32x4 acc[2][4];
  zero_acc32(acc);
  mfma_tiles32(B, Wt_ew2, 256, l, w, acc);
  __syncthreads();                     // all reads of EH done
  // write ea1 back into B (same swizzled layout)
  #pragma unroll
  for (int mi = 0; mi < 2; mi++)
  #pragma unroll
  for (int ni = 0; ni < 4; ni++){
    const int col = (w * 4 + ni) * 16 + (l & 15);
    const float bb = b2[col];
    #pragma unroll
    for (int r = 0; r < 4; r++){
      const int row = mi * 16 + (l >> 4) * 4 + r;
      *(unsigned short*)((char*)B + row * 512 + ((2 * col) ^ ((row & 7) << 4)))
          = f2bf(acc[mi][ni][r] + bb);
    }
  }
  __syncthreads();
  // coalesced copy B -> EA1 (global)
  {
    const int r = t >> 3, q = t & 7;
    char* gdst = (char*)EA1 + (size_t)(e0 + r) * 512 + q * 64;
    #pragma unroll
    for (int u = 0; u < 4; u++){
      const int cb = q * 64 + u * 16;
      *(bf16x8*)(gdst + u * 16) =
        *(const bf16x8*)((const char*)B + r * 512 + (cb ^ ((r & 7) << 4)));
    }
  }
  // GEMM2: msg + atomic scatter
  zero_acc32(acc);
  mfma_tiles32(B, Wt_wme, 256, l, w, acc);
  #pragma unroll
  for (int mi = 0; mi < 2; mi++)
  #pragma unroll
  for (int ni = 0; ni < 4; ni++){
    const int col = (w * 4 + ni) * 16 + (l & 15);
    const float bb = bm[col];
    #pragma unroll
    for (int r = 0; r < 4; r++){
      const int row = mi * 16 + (l >> 4) * 4 + r;
      const int e = e0 + row;
      const int sv = clampi(ei[e]);
      const int dv = clampi(ei[N_EDGES + e]);
      float v = acc[mi][ni][r] + bb + bf2f(P0h[(size_t)sv * 768 + 512 + col]);
      v = fmaxf(v, 0.f);
      atomicAdd(&S[(size_t)dv * 256 + col], v);
    }
  }
}

// ---------------- layer-1 fused edge pass + predictor head (32-edge tile) ---
// eh1 = relu(ea1 @ W1c1 + pA1[src] + pB1[dst] + b1)
// ea2 = eh1 @ e_w2_1 + b2 + ea1
// out = relu(ea2 @ p_w1 + p_b1) . p_w2 + p_b2
__global__ __launch_bounds__(256, 4) void edge_pass1(
    const int* __restrict__ ei,
    const unsigned short* __restrict__ EA1,
    const unsigned short* __restrict__ P1h,  // [N][512] bf16 = pA1|pB1
    const float* __restrict__ b1,            // e_b1_1
    const unsigned short* __restrict__ Wt_w1c,
    const unsigned short* __restrict__ Wt_ew2,
    const float* __restrict__ b2,            // e_b2_1
    const unsigned short* __restrict__ Wt_pw1,
    const float* __restrict__ pb1,
    const float* __restrict__ pw2,
    const float* __restrict__ pb2,
    float* __restrict__ out)
{
  __shared__ __align__(16) unsigned short B[EROWS * 256];
  __shared__ float partial[128];
  const int t = threadIdx.x, w = t >> 6, l = t & 63;
  const int e0 = blockIdx.x * EROWS;
  // load ea1 tile -> B (swizzled)
  {
    const int r = t >> 3, q = t & 7;
    const char* gsrc = (const char*)EA1 + (size_t)(e0 + r) * 512 + q * 64;
    #pragma unroll
    for (int u = 0; u < 4; u++){
      const int cb = q * 64 + u * 16;
      *(bf16x8*)((char*)B + r * 512 + (cb ^ ((r & 7) << 4))) = *(const bf16x8*)(gsrc + u * 16);
    }
  }
  __syncthreads();
  // GEMM_a: eh1 in acc
  f32x4 acc[2][4];
  zero_acc32(acc);
  mfma_tiles32(B, Wt_w1c, 256, l, w, acc);
  // residual: read this wave's C-quadrant of ea1 from B before overwrite
  unsigned res[2][4][2];
  #pragma unroll
  for (int mi = 0; mi < 2; mi++)
  #pragma unroll
  for (int ni = 0; ni < 4; ni++){
    const int col = (w * 4 + ni) * 16 + (l & 15);
    #pragma unroll
    for (int rp = 0; rp < 2; rp++){
      const int row0 = mi * 16 + (l >> 4) * 4 + rp * 2;
      unsigned a0 = *(const unsigned short*)((const char*)B + row0 * 512 + ((2 * col) ^ ((row0 & 7) << 4)));
      const int row1 = row0 + 1;
      unsigned a1 = *(const unsigned short*)((const char*)B + row1 * 512 + ((2 * col) ^ ((row1 & 7) << 4)));
      res[mi][ni][rp] = a0 | (a1 << 16);
    }
  }
  __syncthreads();
  // write eh1 into B (with P1 gathers + relu)
  #pragma unroll
  for (int mi = 0; mi < 2; mi++)
  #pragma unroll
  for (int ni = 0; ni < 4; ni++){
    const int col = (w * 4 + ni) * 16 + (l & 15);
    const float bb = b1[col];
    #pragma unroll
    for (int r = 0; r < 4; r++){
      const int row = mi * 16 + (l >> 4) * 4 + r;
      const int e = e0 + row;
      const int sv = clampi(ei[e]);
      const int dv = clampi(ei[N_EDGES + e]);
      float v = acc[mi][ni][r] + bb + bf2f(P1h[(size_t)sv * 512 + col])
              + bf2f(P1h[(size_t)dv * 512 + 256 + col]);
      *(unsigned short*)((char*)B + row * 512 + ((2 * col) ^ ((row & 7) << 4)))
          = f2bf(fmaxf(v, 0.f));
    }
  }
  __syncthreads();
  // GEMM_b: ea2 = eh1 @ W2 + b2 + ea1
  zero_acc32(acc);
  mfma_tiles32(B, Wt_ew2, 256, l, w, acc);
  __syncthreads();
  #pragma unroll
  for (int mi = 0; mi < 2; mi++)
  #pragma unroll
  for (int ni = 0; ni < 4; ni++){
    const int col = (w * 4 + ni) * 16 + (l & 15);
    const float bb = b2[col];
    #pragma unroll
    for (int rp = 0; rp < 2; rp++){
      const unsigned rr = res[mi][ni][rp];
      const int row0 = mi * 16 + (l >> 4) * 4 + rp * 2;
      const int row1 = row0 + 1;
      float v0 = acc[mi][ni][rp * 2 + 0] + bb + bf2f((unsigned short)(rr & 0xffff));
      float v1 = acc[mi][ni][rp * 2 + 1] + bb + bf2f((unsigned short)(rr >> 16));
      *(unsigned short*)((char*)B + row0 * 512 + ((2 * col) ^ ((row0 & 7) << 4))) = f2bf(v0);
      *(unsigned short*)((char*)B + row1 * 512 + ((2 * col) ^ ((row1 & 7) << 4))) = f2bf(v1);
    }
  }
  __syncthreads();
  // GEMM_c: h = relu(ea2 @ p_w1 + pb1); rowsum(h * pw2)
  zero_acc32(acc);
  mfma_tiles32(B, Wt_pw1, 256, l, w, acc);
  {
    float rs[2][4];
    #pragma unroll
    for (int mi = 0; mi < 2; mi++)
      #pragma unroll
      for (int r = 0; r < 4; r++) rs[mi][r] = 0.f;
    #pragma unroll
    for (int mi = 0; mi < 2; mi++)
    #pragma unroll
    for (int ni = 0; ni < 4; ni++){
      const int col = (w * 4 + ni) * 16 + (l & 15);
      const float pb = pb1[col];
      const float pw = pw2[col];
      #pragma unroll
      for (int r = 0; r < 4; r++)
        rs[mi][r] += fmaxf(acc[mi][ni][r] + pb, 0.f) * pw;
    }
    #pragma unroll
    for (int off = 1; off < 16; off <<= 1){
      #pragma unroll
      for (int mi = 0; mi < 2; mi++)
        #pragma unroll
        for (int r = 0; r < 4; r++)
          rs[mi][r] += __shfl_xor(rs[mi][r], off);
    }
    if ((l & 15) == 0){
      #pragma unroll
      for (int mi = 0; mi < 2; mi++)
        #pragma unroll
        for (int r = 0; r < 4; r++)
          partial[w * 32 + mi * 16 + (l >> 4) * 4 + r] = rs[mi][r];
    }
  }
  __syncthreads();
  if (t < EROWS)
    out[e0 + t] = partial[t] + partial[32 + t] + partial[64 + t] + partial[96 + t] + pb2[0];
}

// ---------------- host ----------------
extern "C" void kernel_launch(void* const* d_in, const int* in_sizes, int n_in,
                              void* d_out, int out_size, void* d_ws, size_t ws_size,
                              hipStream_t stream)
{
  const float* x      = (const float*)d_in[0];
  const int* ei       = (const int*)d_in[1];        // int32 per harness contract
  const float* eattr  = (const float*)d_in[2];
  const float* e_w1_0 = (const float*)d_in[3];
  const float* e_b1_0 = (const float*)d_in[4];
  const float* e_w2_0 = (const float*)d_in[5];
  const float* e_b2_0 = (const float*)d_in[6];
  const float* n_wm_0 = (const float*)d_in[7];
  const float* n_bm_0 = (const float*)d_in[8];
  const float* n_w1_0 = (const float*)d_in[9];
  const float* n_b1_0 = (const float*)d_in[10];
  const float* n_w2_0 = (const float*)d_in[11];
  const float* n_b2_0 = (const float*)d_in[12];
  const float* e_w1_1 = (const float*)d_in[13];
  const float* e_b1_1 = (const float*)d_in[14];
  const float* e_w2_1 = (const float*)d_in[15];
  const float* e_b2_1 = (const float*)d_in[16];
  // d_in[17..22] (layer-1 node model) are dead code for the output
  const float* p_w1   = (const float*)d_in[23];
  const float* p_b1   = (const float*)d_in[24];
  const float* p_w2   = (const float*)d_in[25];
  const float* p_b2   = (const float*)d_in[26];
  float* out = (float*)d_out;

  char* base = (char*)d_ws;
  size_t off = 0;
  auto take = [&](size_t bytes)->void*{
    void* p = base + off;
    off = (off + bytes + 255) & ~(size_t)255;
    return p;
  };
  unsigned short* WtP0   = (unsigned short*)take((size_t)768 * 512 * 2);
  unsigned short* Wtew20 = (unsigned short*)take((size_t)256 * 256 * 2);
  unsigned short* Wtwme0 = (unsigned short*)take((size_t)256 * 256 * 2);
  unsigned short* Wtnw1  = (unsigned short*)take((size_t)256 * 768 * 2);
  unsigned short* Wtnw2  = (unsigned short*)take((size_t)256 * 256 * 2);
  unsigned short* WtP1   = (unsigned short*)take((size_t)512 * 256 * 2);
  unsigned short* Wtw1c1 = (unsigned short*)take((size_t)256 * 256 * 2);
  unsigned short* Wtew21 = (unsigned short*)take((size_t)256 * 256 * 2);
  unsigned short* Wtpw1  = (unsigned short*)take((size_t)256 * 256 * 2);
  // Region A (15.36MB): P0h (bf16 [10000][768]) lives here during layer 0.
  // After edge_pass0 it is dead: NH (f32, 10.24MB) overlays it, then P1h
  // (bf16, 10.24MB) overlays again after NH is consumed.
  char* regionA = (char*)take((size_t)N_NODES * 768 * 2);
  unsigned short* P0h = (unsigned short*)regionA;
  float* NH           = (float*)regionA;
  unsigned short* P1h = (unsigned short*)regionA;
  float* S   = (float*)take((size_t)N_NODES * 256 * 4);
  float* X1  = S;    // X1 computed after S is dead
  float* CNT = (float*)take((size_t)N_NODES * 4);
  unsigned short* EA1 = (unsigned short*)take((size_t)N_EDGES * 256 * 2);
  (void)ws_size; (void)in_sizes; (void)n_in; (void)out_size;

  TJobs jobs;
  auto J = [&](int idx, const float* in, unsigned short* outp, int K, int N, int row0, int ld){
    jobs.j[idx].in = in; jobs.j[idx].out = outp; jobs.j[idx].K = K;
    jobs.j[idx].N = N; jobs.j[idx].row0 = row0; jobs.j[idx].ld = ld;
  };
  J(0,  e_w1_0, WtP0,            512, 256,   0, 256);  // pA0
  J(1,  e_w1_0, WtP0 + 256*512,  512, 256, 512, 256);  // pB0
  J(2,  n_wm_0, WtP0 + 512*512,  512, 256,   0, 256);  // pM0
  J(3,  e_w2_0, Wtew20, 256, 256,   0, 256);
  J(4,  n_wm_0, Wtwme0, 256, 256, 512, 256);
  J(5,  n_w1_0, Wtnw1,  768, 256,   0, 256);
  J(6,  n_w2_0, Wtnw2,  256, 256,   0, 256);
  J(7,  e_w1_1, WtP1,            256, 256,   0, 256);  // pA1
  J(8,  e_w1_1, WtP1 + 256*256,  256, 256, 256, 256);  // pB1
  J(9,  e_w1_1, Wtw1c1, 256, 256, 512, 256);
  J(10, e_w2_1, Wtew21, 256, 256,   0, 256);
  J(11, p_w1,   Wtpw1,  256, 256,   0, 256);
  prep_weights<<<dim3(768, 12), 256, 0, stream>>>(jobs);

  hipMemsetAsync(S, 0, (size_t)N_NODES * 256 * 4, stream);
  hipMemsetAsync(CNT, 0, (size_t)N_NODES * 4, stream);

  const int NT = (N_NODES + 63) / 64;   // 157
  // P0h = bf16( x @ [pA0|pB0|pM0] )
  gemm_nodes<<<dim3(NT, 3), 256, 0, stream>>>(x, 512, nullptr, 0, WtP0, nullptr, P0h, 768, 0, 1, nullptr);
  edge_pass0<<<N_EDGES / EROWS, 256, 0, stream>>>(ei, eattr, P0h, e_w1_0 + 1024 * 256, e_b1_0,
                                                  Wtew20, e_b2_0, Wtwme0, n_bm_0, EA1, S, CNT);
  // NH = relu([x | S/cnt] @ n_w1_0 + b)   (mean-normalize fused; NH overlays dead P0h)
  gemm_nodes<<<dim3(NT, 1), 256, 0, stream>>>(x, 512, S, 256, Wtnw1, n_b1_0, NH, 256, 1, 0, CNT);
  // X1 = NH @ n_w2_0 + b                  (X1 overlays dead S)
  gemm_nodes<<<dim3(NT, 1), 256, 0, stream>>>(NH, 256, nullptr, 0, Wtnw2, n_b2_0, X1, 256, 0, 0, nullptr);
  // P1h = bf16( X1 @ [pA1|pB1] )          (overlays region A after NH is consumed)
  gemm_nodes<<<dim3(NT, 2), 256, 0, stream>>>(X1, 256, nullptr, 0, WtP1, nullptr, P1h, 512, 0, 1, nullptr);
  edge_pass1<<<N_EDGES / EROWS, 256, 0, stream>>>(ei, EA1, P1h, e_b1_1, Wtw1c1, Wtew21, e_b2_1,
                                                  Wtpw1, p_b1, p_w2, p_b2, out);
}

// Round 6
// 889.095 us; speedup vs baseline: 1.2460x; 1.0538x over previous
//
#include <hip/hip_runtime.h>
#include <stdint.h>

#define N_NODES 10000
#define N_EDGES 160000
#define EROWS 32

typedef __attribute__((ext_vector_type(8))) short bf16x8;
typedef __attribute__((ext_vector_type(4))) float f32x4;
typedef __attribute__((ext_vector_type(4))) unsigned short ushort4v;

__device__ __forceinline__ unsigned short f2bf(float f){
  union { float f; unsigned u; } v; v.f = f;
  unsigned u = v.u;
  u += 0x7fffu + ((u >> 16) & 1u);       // round-to-nearest-even
  return (unsigned short)(u >> 16);
}
__device__ __forceinline__ float bf2f(unsigned short h){
  union { unsigned u; float f; } v; v.u = ((unsigned)h) << 16; return v.f;
}
__device__ __forceinline__ int clampi(int v){
  return v < 0 ? 0 : (v >= N_NODES ? N_NODES - 1 : v);
}

// ---------------- weight transpose + bf16 convert ----------------
struct TJob { const float* in; unsigned short* out; int K; int N; int row0; int ld; };
struct TJobs { TJob j[12]; };

__global__ __launch_bounds__(256) void prep_weights(TJobs jobs){
  TJob jb = jobs.j[blockIdx.y];
  int total = jb.K * jb.N;
  int i = blockIdx.x * 256 + threadIdx.x;
  if (i >= total) return;
  int n = i / jb.K;
  int k = i - n * jb.K;
  jb.out[(size_t)n * jb.K + k] = f2bf(jb.in[(size_t)(jb.row0 + k) * jb.ld + n]);
}

// ---------------- counting sort of edges by dst ----------------
__global__ __launch_bounds__(256) void hist_k(const int* __restrict__ ei, int* __restrict__ HIST){
  int e = blockIdx.x * 256 + threadIdx.x;
  if (e < N_EDGES) atomicAdd(&HIST[clampi(ei[N_EDGES + e])], 1);
}

__global__ __launch_bounds__(1024) void scan_k(const int* __restrict__ HIST,
                                               int* __restrict__ OFFW,
                                               float* __restrict__ CNTf){
  __shared__ int ps[1024];
  const int t = threadIdx.x;
  int loc[10]; int s = 0;
  #pragma unroll
  for (int i = 0; i < 10; i++){
    int idx = t * 10 + i;
    int v = (idx < N_NODES) ? HIST[idx] : 0;
    loc[i] = s; s += v;
  }
  ps[t] = s; __syncthreads();
  const int mine = s;
  for (int o = 1; o < 1024; o <<= 1){
    int v = (t >= o) ? ps[t - o] : 0;
    __syncthreads();
    ps[t] += v;
    __syncthreads();
  }
  const int excl = ps[t] - mine;
  #pragma unroll
  for (int i = 0; i < 10; i++){
    int idx = t * 10 + i;
    if (idx < N_NODES){
      OFFW[idx] = excl + loc[i];
      CNTf[idx] = (float)HIST[idx];
    }
  }
}

__global__ __launch_bounds__(256) void perm_k(const int* __restrict__ ei,
                                              int* __restrict__ OFFW,
                                              int* __restrict__ perm){
  int e = blockIdx.x * 256 + threadIdx.x;
  if (e < N_EDGES){
    int d = clampi(ei[N_EDGES + e]);
    int pos = atomicAdd(&OFFW[d], 1);
    perm[pos] = e;
  }
}

// ---- MFMA over a [ROWS][256] bf16 LDS tile, per-wave 32x64 output ----------
// A: LDS XOR-swizzled: byte = row*512 + (colbyte ^ ((row&7)<<4))
// Wt: row-major [outCols][wstride] bf16. Wave w computes cols w*64..w*64+63.
__device__ __forceinline__ void mfma_tiles32(const unsigned short* __restrict__ A,
                                             const unsigned short* __restrict__ Wt,
                                             int wstride, int l, int w, f32x4 acc[2][4])
{
  #pragma unroll
  for (int ks = 0; ks < 8; ks++){
    const int kb = ks * 64 + ((l >> 4) << 4);     // byte offset of this lane's 8 bf16
    bf16x8 a[2];
    #pragma unroll
    for (int mi = 0; mi < 2; mi++){
      const int row = mi * 16 + (l & 15);
      a[mi] = *(const bf16x8*)((const char*)A + row * 512 + (kb ^ ((row & 7) << 4)));
    }
    #pragma unroll
    for (int ni = 0; ni < 4; ni++){
      const unsigned short* bp = Wt + (size_t)((w * 4 + ni) * 16 + (l & 15)) * wstride;
      bf16x8 b = *(const bf16x8*)((const char*)bp + kb);
      #pragma unroll
      for (int mi = 0; mi < 2; mi++)
        acc[mi][ni] = __builtin_amdgcn_mfma_f32_16x16x32_bf16(a[mi], b, acc[mi][ni], 0, 0, 0);
    }
  }
}
__device__ __forceinline__ void zero_acc32(f32x4 acc[2][4]){
  #pragma unroll
  for (int mi = 0; mi < 2; mi++)
    #pragma unroll
    for (int ni = 0; ni < 4; ni++)
      acc[mi][ni] = (f32x4){0.f, 0.f, 0.f, 0.f};
}

// ---- 64-row variant for node GEMMs ---------
__device__ __forceinline__ void mfma_tiles64(const unsigned short* __restrict__ A,
                                             const unsigned short* __restrict__ Wt,
                                             int wstride, int l, int w, f32x4 acc[4][4])
{
  #pragma unroll
  for (int ks = 0; ks < 8; ks++){
    const int kb = ks * 64 + ((l >> 4) << 4);
    bf16x8 a[4];
    #pragma unroll
    for (int mi = 0; mi < 4; mi++){
      const int row = mi * 16 + (l & 15);
      a[mi] = *(const bf16x8*)((const char*)A + row * 512 + (kb ^ ((row & 7) << 4)));
    }
    #pragma unroll
    for (int ni = 0; ni < 4; ni++){
      const unsigned short* bp = Wt + (size_t)((w * 4 + ni) * 16 + (l & 15)) * wstride;
      bf16x8 b = *(const bf16x8*)((const char*)bp + kb);
      #pragma unroll
      for (int mi = 0; mi < 4; mi++)
        acc[mi][ni] = __builtin_amdgcn_mfma_f32_16x16x32_bf16(a[mi], b, acc[mi][ni], 0, 0, 0);
    }
  }
}

// ---------------- generic node GEMM: C = act([A1|A2/cnt] @ Wt + bias) -------
__global__ __launch_bounds__(256) void gemm_nodes(
    const float* __restrict__ A1, int K1,
    const float* __restrict__ A2, int K2,
    const unsigned short* __restrict__ Wt,   // [NcTot][Ktot]
    const float* __restrict__ bias,
    void* __restrict__ Cout, int NcTot, int relu, int out_bf16,
    const float* __restrict__ cnt)           // if set: divide A2 rows by max(cnt,1)
{
  __shared__ __align__(16) unsigned short As[64 * 256];
  const int t = threadIdx.x, w = t >> 6, l = t & 63;
  const int rowBase = blockIdx.x * 64;
  const int bc = blockIdx.y;
  const int Ktot = K1 + K2;
  f32x4 acc[4][4] = {};
  for (int kc = 0; kc < Ktot; kc += 256){
    __syncthreads();
    {
      const int r = t >> 2, q = t & 3;
      int rg = rowBase + r; if (rg >= N_NODES) rg = N_NODES - 1;
      const int inA2 = (kc >= K1);
      const float* src = !inA2 ? (A1 + (size_t)rg * K1 + kc)
                               : (A2 + (size_t)rg * K2 + (kc - K1));
      const float inv = (cnt && inA2) ? (1.f / fmaxf(cnt[rg], 1.f)) : 1.f;
      #pragma unroll
      for (int u = 0; u < 16; u++){
        const int cb = q * 128 + u * 8;
        f32x4 v = *(const f32x4*)(src + q * 64 + u * 4);
        ushort4v h;
        h[0] = f2bf(v[0] * inv); h[1] = f2bf(v[1] * inv);
        h[2] = f2bf(v[2] * inv); h[3] = f2bf(v[3] * inv);
        *(ushort4v*)((char*)As + r * 512 + (cb ^ ((r & 7) << 4))) = h;
      }
    }
    __syncthreads();
    mfma_tiles64(As, Wt + (size_t)(bc * 256) * Ktot + kc, Ktot, l, w, acc);
  }
  #pragma unroll
  for (int mi = 0; mi < 4; mi++)
  #pragma unroll
  for (int ni = 0; ni < 4; ni++){
    const int colAbs = bc * 256 + (w * 4 + ni) * 16 + (l & 15);
    const float bv = bias ? bias[colAbs] : 0.f;
    #pragma unroll
    for (int r = 0; r < 4; r++){
      const int rowg = rowBase + mi * 16 + (l >> 4) * 4 + r;
      if (rowg < N_NODES){
        float v = acc[mi][ni][r] + bv;
        if (relu) v = fmaxf(v, 0.f);
        if (out_bf16) ((unsigned short*)Cout)[(size_t)rowg * NcTot + colAbs] = f2bf(v);
        else          ((float*)Cout)[(size_t)rowg * NcTot + colAbs] = v;
      }
    }
  }
}

// ---------------- layer-0 fused edge pass (dst-sorted, segmented scatter) ---
// Processes edges in dst-sorted order (perm). Per 32-edge tile:
//   EH = relu(pA0[src] + pB0[dst] + ea@W1c + b1)      -> B
//   ea1 = EH @ e_w2_0 + b2                            -> B, copy to EA1[orig e]
//   msg = relu(ea1 @ Wm_e + pM0[src] + bm)            -> B
//   column-wise segmented sum over dst-runs -> few atomics into S
__global__ __launch_bounds__(256, 4) void edge_pass0(
    const int* __restrict__ ei,
    const float* __restrict__ ea,
    const unsigned short* __restrict__ P0h,  // [N][768] bf16 = pA0|pB0|pM0
    const float* __restrict__ W1c,           // [6][256] f32
    const float* __restrict__ b1,
    const unsigned short* __restrict__ Wt_ew2,
    const float* __restrict__ b2,
    const unsigned short* __restrict__ Wt_wme,
    const float* __restrict__ bm,
    const int* __restrict__ perm,
    unsigned short* __restrict__ EA1,
    float* __restrict__ S)
{
  __shared__ __align__(16) unsigned short B[EROWS * 256];
  __shared__ int eids[EROWS];
  __shared__ int dsts[EROWS];
  const int t = threadIdx.x, w = t >> 6, l = t & 63;
  const int p0 = blockIdx.x * EROWS;
  if (t < EROWS){
    const int e = perm[p0 + t];
    eids[t] = e;
    dsts[t] = clampi(ei[N_EDGES + e]);
  }
  __syncthreads();
  // phase E: EH -> B   (8 threads per edge row, 32 cols each)
  {
    const int r = t >> 3, q = t & 7;
    const int e = eids[r];
    const int sv = clampi(ei[e]);
    const int dv = dsts[r];
    const unsigned short* pa = P0h + (size_t)sv * 768;
    const unsigned short* pb = P0h + (size_t)dv * 768 + 256;
    float eav[6];
    #pragma unroll
    for (int k = 0; k < 6; k++) eav[k] = ea[(size_t)e * 6 + k];
    #pragma unroll
    for (int u = 0; u < 4; u++){
      const int c = q * 32 + u * 8;
      bf16x8 va = *(const bf16x8*)(pa + c);
      bf16x8 vb = *(const bf16x8*)(pb + c);
      bf16x8 h;
      #pragma unroll
      for (int j = 0; j < 8; j++){
        float v = bf2f((unsigned short)va[j]) + bf2f((unsigned short)vb[j]) + b1[c + j];
        #pragma unroll
        for (int k = 0; k < 6; k++) v += eav[k] * W1c[k * 256 + c + j];
        h[j] = (short)f2bf(fmaxf(v, 0.f));
      }
      *(bf16x8*)((char*)B + r * 512 + ((2 * c) ^ ((r & 7) << 4))) = h;
    }
  }
  __syncthreads();
  // GEMM1: ea1 in acc
  f32x4 acc[2][4];
  zero_acc32(acc);
  mfma_tiles32(B, Wt_ew2, 256, l, w, acc);
  __syncthreads();                     // all reads of EH done
  // write ea1 back into B (same swizzled layout)
  #pragma unroll
  for (int mi = 0; mi < 2; mi++)
  #pragma unroll
  for (int ni = 0; ni < 4; ni++){
    const int col = (w * 4 + ni) * 16 + (l & 15);
    const float bb = b2[col];
    #pragma unroll
    for (int r = 0; r < 4; r++){
      const int row = mi * 16 + (l >> 4) * 4 + r;
      *(unsigned short*)((char*)B + row * 512 + ((2 * col) ^ ((row & 7) << 4)))
          = f2bf(acc[mi][ni][r] + bb);
    }
  }
  __syncthreads();
  // copy B -> EA1 rows at ORIGINAL edge ids (512B contiguous per row)
  {
    const int r = t >> 3, q = t & 7;
    char* gdst = (char*)EA1 + (size_t)eids[r] * 512 + q * 64;
    #pragma unroll
    for (int u = 0; u < 4; u++){
      const int cb = q * 64 + u * 16;
      *(bf16x8*)(gdst + u * 16) =
        *(const bf16x8*)((const char*)B + r * 512 + (cb ^ ((r & 7) << 4)));
    }
  }
  // GEMM2: msg
  zero_acc32(acc);
  mfma_tiles32(B, Wt_wme, 256, l, w, acc);
  __syncthreads();                     // all reads of ea1 done (copy + mfma)
  // write msg into B (with pM0 gather + relu)
  #pragma unroll
  for (int mi = 0; mi < 2; mi++)
  #pragma unroll
  for (int ni = 0; ni < 4; ni++){
    const int col = (w * 4 + ni) * 16 + (l & 15);
    const float bb = bm[col];
    #pragma unroll
    for (int r = 0; r < 4; r++){
      const int row = mi * 16 + (l >> 4) * 4 + r;
      const int sv = clampi(ei[eids[row]]);
      float v = acc[mi][ni][r] + bb + bf2f(P0h[(size_t)sv * 768 + 512 + col]);
      *(unsigned short*)((char*)B + row * 512 + ((2 * col) ^ ((row & 7) << 4)))
          = f2bf(fmaxf(v, 0.f));
    }
  }
  __syncthreads();
  // column-wise segmented reduction over dst-runs (thread = column; branches
  // are wave-uniform since dsts[r] is the same for all lanes)
  {
    const int col = t;
    float sum = 0.f;
    int cur = dsts[0];
    for (int r = 0; r < EROWS; r++){
      const int d = dsts[r];
      if (d != cur){
        atomicAdd(&S[(size_t)cur * 256 + col], sum);
        sum = 0.f; cur = d;
      }
      sum += bf2f(*(const unsigned short*)((const char*)B + r * 512 + ((2 * col) ^ ((r & 7) << 4))));
    }
    atomicAdd(&S[(size_t)cur * 256 + col], sum);
  }
}

// ---------------- layer-1 fused edge pass + predictor head (32-edge tile) ---
__global__ __launch_bounds__(256, 4) void edge_pass1(
    const int* __restrict__ ei,
    const unsigned short* __restrict__ EA1,
    const unsigned short* __restrict__ P1h,  // [N][512] bf16 = pA1|pB1
    const float* __restrict__ b1,            // e_b1_1
    const unsigned short* __restrict__ Wt_w1c,
    const unsigned short* __restrict__ Wt_ew2,
    const float* __restrict__ b2,            // e_b2_1
    const unsigned short* __restrict__ Wt_pw1,
    const float* __restrict__ pb1,
    const float* __restrict__ pw2,
    const float* __restrict__ pb2,
    float* __restrict__ out)
{
  __shared__ __align__(16) unsigned short B[EROWS * 256];
  __shared__ float partial[128];
  const int t = threadIdx.x, w = t >> 6, l = t & 63;
  const int e0 = blockIdx.x * EROWS;
  // load ea1 tile -> B (swizzled)
  {
    const int r = t >> 3, q = t & 7;
    const char* gsrc = (const char*)EA1 + (size_t)(e0 + r) * 512 + q * 64;
    #pragma unroll
    for (int u = 0; u < 4; u++){
      const int cb = q * 64 + u * 16;
      *(bf16x8*)((char*)B + r * 512 + (cb ^ ((r & 7) << 4))) = *(const bf16x8*)(gsrc + u * 16);
    }
  }
  __syncthreads();
  // GEMM_a: eh1 in acc
  f32x4 acc[2][4];
  zero_acc32(acc);
  mfma_tiles32(B, Wt_w1c, 256, l, w, acc);
  // residual: read this wave's C-quadrant of ea1 from B before overwrite
  unsigned res[2][4][2];
  #pragma unroll
  for (int mi = 0; mi < 2; mi++)
  #pragma unroll
  for (int ni = 0; ni < 4; ni++){
    const int col = (w * 4 + ni) * 16 + (l & 15);
    #pragma unroll
    for (int rp = 0; rp < 2; rp++){
      const int row0 = mi * 16 + (l >> 4) * 4 + rp * 2;
      unsigned a0 = *(const unsigned short*)((const char*)B + row0 * 512 + ((2 * col) ^ ((row0 & 7) << 4)));
      const int row1 = row0 + 1;
      unsigned a1 = *(const unsigned short*)((const char*)B + row1 * 512 + ((2 * col) ^ ((row1 & 7) << 4)));
      res[mi][ni][rp] = a0 | (a1 << 16);
    }
  }
  __syncthreads();
  // write eh1 into B (with P1 gathers + relu)
  #pragma unroll
  for (int mi = 0; mi < 2; mi++)
  #pragma unroll
  for (int ni = 0; ni < 4; ni++){
    const int col = (w * 4 + ni) * 16 + (l & 15);
    const float bb = b1[col];
    #pragma unroll
    for (int r = 0; r < 4; r++){
      const int row = mi * 16 + (l >> 4) * 4 + r;
      const int e = e0 + row;
      const int sv = clampi(ei[e]);
      const int dv = clampi(ei[N_EDGES + e]);
      float v = acc[mi][ni][r] + bb + bf2f(P1h[(size_t)sv * 512 + col])
              + bf2f(P1h[(size_t)dv * 512 + 256 + col]);
      *(unsigned short*)((char*)B + row * 512 + ((2 * col) ^ ((row & 7) << 4)))
          = f2bf(fmaxf(v, 0.f));
    }
  }
  __syncthreads();
  // GEMM_b: ea2 = eh1 @ W2 + b2 + ea1
  zero_acc32(acc);
  mfma_tiles32(B, Wt_ew2, 256, l, w, acc);
  __syncthreads();
  #pragma unroll
  for (int mi = 0; mi < 2; mi++)
  #pragma unroll
  for (int ni = 0; ni < 4; ni++){
    const int col = (w * 4 + ni) * 16 + (l & 15);
    const float bb = b2[col];
    #pragma unroll
    for (int rp = 0; rp < 2; rp++){
      const unsigned rr = res[mi][ni][rp];
      const int row0 = mi * 16 + (l >> 4) * 4 + rp * 2;
      const int row1 = row0 + 1;
      float v0 = acc[mi][ni][rp * 2 + 0] + bb + bf2f((unsigned short)(rr & 0xffff));
      float v1 = acc[mi][ni][rp * 2 + 1] + bb + bf2f((unsigned short)(rr >> 16));
      *(unsigned short*)((char*)B + row0 * 512 + ((2 * col) ^ ((row0 & 7) << 4))) = f2bf(v0);
      *(unsigned short*)((char*)B + row1 * 512 + ((2 * col) ^ ((row1 & 7) << 4))) = f2bf(v1);
    }
  }
  __syncthreads();
  // GEMM_c: h = relu(ea2 @ p_w1 + pb1); rowsum(h * pw2)
  zero_acc32(acc);
  mfma_tiles32(B, Wt_pw1, 256, l, w, acc);
  {
    float rs[2][4];
    #pragma unroll
    for (int mi = 0; mi < 2; mi++)
      #pragma unroll
      for (int r = 0; r < 4; r++) rs[mi][r] = 0.f;
    #pragma unroll
    for (int mi = 0; mi < 2; mi++)
    #pragma unroll
    for (int ni = 0; ni < 4; ni++){
      const int col = (w * 4 + ni) * 16 + (l & 15);
      const float pb = pb1[col];
      const float pw = pw2[col];
      #pragma unroll
      for (int r = 0; r < 4; r++)
        rs[mi][r] += fmaxf(acc[mi][ni][r] + pb, 0.f) * pw;
    }
    #pragma unroll
    for (int off = 1; off < 16; off <<= 1){
      #pragma unroll
      for (int mi = 0; mi < 2; mi++)
        #pragma unroll
        for (int r = 0; r < 4; r++)
          rs[mi][r] += __shfl_xor(rs[mi][r], off);
    }
    if ((l & 15) == 0){
      #pragma unroll
      for (int mi = 0; mi < 2; mi++)
        #pragma unroll
        for (int r = 0; r < 4; r++)
          partial[w * 32 + mi * 16 + (l >> 4) * 4 + r] = rs[mi][r];
    }
  }
  __syncthreads();
  if (t < EROWS)
    out[e0 + t] = partial[t] + partial[32 + t] + partial[64 + t] + partial[96 + t] + pb2[0];
}

// ---------------- host ----------------
extern "C" void kernel_launch(void* const* d_in, const int* in_sizes, int n_in,
                              void* d_out, int out_size, void* d_ws, size_t ws_size,
                              hipStream_t stream)
{
  const float* x      = (const float*)d_in[0];
  const int* ei       = (const int*)d_in[1];        // int32 per harness contract
  const float* eattr  = (const float*)d_in[2];
  const float* e_w1_0 = (const float*)d_in[3];
  const float* e_b1_0 = (const float*)d_in[4];
  const float* e_w2_0 = (const float*)d_in[5];
  const float* e_b2_0 = (const float*)d_in[6];
  const float* n_wm_0 = (const float*)d_in[7];
  const float* n_bm_0 = (const float*)d_in[8];
  const float* n_w1_0 = (const float*)d_in[9];
  const float* n_b1_0 = (const float*)d_in[10];
  const float* n_w2_0 = (const float*)d_in[11];
  const float* n_b2_0 = (const float*)d_in[12];
  const float* e_w1_1 = (const float*)d_in[13];
  const float* e_b1_1 = (const float*)d_in[14];
  const float* e_w2_1 = (const float*)d_in[15];
  const float* e_b2_1 = (const float*)d_in[16];
  // d_in[17..22] (layer-1 node model) are dead code for the output
  const float* p_w1   = (const float*)d_in[23];
  const float* p_b1   = (const float*)d_in[24];
  const float* p_w2   = (const float*)d_in[25];
  const float* p_b2   = (const float*)d_in[26];
  float* out = (float*)d_out;

  char* base = (char*)d_ws;
  size_t off = 0;
  auto take = [&](size_t bytes)->void*{
    void* p = base + off;
    off = (off + bytes + 255) & ~(size_t)255;
    return p;
  };
  unsigned short* WtP0   = (unsigned short*)take((size_t)768 * 512 * 2);
  unsigned short* Wtew20 = (unsigned short*)take((size_t)256 * 256 * 2);
  unsigned short* Wtwme0 = (unsigned short*)take((size_t)256 * 256 * 2);
  unsigned short* Wtnw1  = (unsigned short*)take((size_t)256 * 768 * 2);
  unsigned short* Wtnw2  = (unsigned short*)take((size_t)256 * 256 * 2);
  unsigned short* WtP1   = (unsigned short*)take((size_t)512 * 256 * 2);
  unsigned short* Wtw1c1 = (unsigned short*)take((size_t)256 * 256 * 2);
  unsigned short* Wtew21 = (unsigned short*)take((size_t)256 * 256 * 2);
  unsigned short* Wtpw1  = (unsigned short*)take((size_t)256 * 256 * 2);
  // Region A (15.36MB): P0h (bf16 [10000][768]) lives here during layer 0.
  // After edge_pass0 it is dead: NH (f32) overlays it, then P1h overlays again.
  char* regionA = (char*)take((size_t)N_NODES * 768 * 2);
  unsigned short* P0h = (unsigned short*)regionA;
  float* NH           = (float*)regionA;
  unsigned short* P1h = (unsigned short*)regionA;
  float* S   = (float*)take((size_t)N_NODES * 256 * 4);
  float* X1  = S;    // X1 computed after S is dead
  float* CNTf = (float*)take((size_t)N_NODES * 4);
  unsigned short* EA1 = (unsigned short*)take((size_t)N_EDGES * 256 * 2);
  int* HIST = (int*)take((size_t)N_NODES * 4);
  int* OFFW = (int*)take((size_t)N_NODES * 4);
  int* perm = (int*)take((size_t)N_EDGES * 4);
  (void)ws_size; (void)in_sizes; (void)n_in; (void)out_size;

  TJobs jobs;
  auto J = [&](int idx, const float* in, unsigned short* outp, int K, int N, int row0, int ld){
    jobs.j[idx].in = in; jobs.j[idx].out = outp; jobs.j[idx].K = K;
    jobs.j[idx].N = N; jobs.j[idx].row0 = row0; jobs.j[idx].ld = ld;
  };
  J(0,  e_w1_0, WtP0,            512, 256,   0, 256);  // pA0
  J(1,  e_w1_0, WtP0 + 256*512,  512, 256, 512, 256);  // pB0
  J(2,  n_wm_0, WtP0 + 512*512,  512, 256,   0, 256);  // pM0
  J(3,  e_w2_0, Wtew20, 256, 256,   0, 256);
  J(4,  n_wm_0, Wtwme0, 256, 256, 512, 256);
  J(5,  n_w1_0, Wtnw1,  768, 256,   0, 256);
  J(6,  n_w2_0, Wtnw2,  256, 256,   0, 256);
  J(7,  e_w1_1, WtP1,            256, 256,   0, 256);  // pA1
  J(8,  e_w1_1, WtP1 + 256*256,  256, 256, 256, 256);  // pB1
  J(9,  e_w1_1, Wtw1c1, 256, 256, 512, 256);
  J(10, e_w2_1, Wtew21, 256, 256,   0, 256);
  J(11, p_w1,   Wtpw1,  256, 256,   0, 256);
  prep_weights<<<dim3(768, 12), 256, 0, stream>>>(jobs);

  hipMemsetAsync(S, 0, (size_t)N_NODES * 256 * 4, stream);
  hipMemsetAsync(HIST, 0, (size_t)N_NODES * 4, stream);

  // ---- counting sort of edges by dst ----
  hist_k<<<(N_EDGES + 255) / 256, 256, 0, stream>>>(ei, HIST);
  scan_k<<<1, 1024, 0, stream>>>(HIST, OFFW, CNTf);
  perm_k<<<(N_EDGES + 255) / 256, 256, 0, stream>>>(ei, OFFW, perm);

  const int NT = (N_NODES + 63) / 64;   // 157
  // P0h = bf16( x @ [pA0|pB0|pM0] )
  gemm_nodes<<<dim3(NT, 3), 256, 0, stream>>>(x, 512, nullptr, 0, WtP0, nullptr, P0h, 768, 0, 1, nullptr);
  edge_pass0<<<N_EDGES / EROWS, 256, 0, stream>>>(ei, eattr, P0h, e_w1_0 + 1024 * 256, e_b1_0,
                                                  Wtew20, e_b2_0, Wtwme0, n_bm_0, perm, EA1, S);
  // NH = relu([x | S/cnt] @ n_w1_0 + b)   (mean-normalize fused; NH overlays dead P0h)
  gemm_nodes<<<dim3(NT, 1), 256, 0, stream>>>(x, 512, S, 256, Wtnw1, n_b1_0, NH, 256, 1, 0, CNTf);
  // X1 = NH @ n_w2_0 + b                  (X1 overlays dead S)
  gemm_nodes<<<dim3(NT, 1), 256, 0, stream>>>(NH, 256, nullptr, 0, Wtnw2, n_b2_0, X1, 256, 0, 0, nullptr);
  // P1h = bf16( X1 @ [pA1|pB1] )          (overlays region A after NH is consumed)
  gemm_nodes<<<dim3(NT, 2), 256, 0, stream>>>(X1, 256, nullptr, 0, WtP1, nullptr, P1h, 512, 0, 1, nullptr);
  edge_pass1<<<N_EDGES / EROWS, 256, 0, stream>>>(ei, EA1, P1h, e_b1_1, Wtw1c1, Wtew21, e_b2_1,
                                                  Wtpw1, p_b1, p_w2, p_b2, out);
}

// Round 7
// 817.770 us; speedup vs baseline: 1.3547x; 1.0872x over previous
//
#include <hip/hip_runtime.h>
#include <stdint.h>

#define N_NODES 10000
#define N_EDGES 160000
#define EROWS 32

typedef __attribute__((ext_vector_type(8))) short bf16x8;
typedef __attribute__((ext_vector_type(4))) float f32x4;
typedef __attribute__((ext_vector_type(4))) unsigned short ushort4v;

__device__ __forceinline__ unsigned short f2bf(float f){
  union { float f; unsigned u; } v; v.f = f;
  unsigned u = v.u;
  u += 0x7fffu + ((u >> 16) & 1u);       // round-to-nearest-even
  return (unsigned short)(u >> 16);
}
__device__ __forceinline__ float bf2f(unsigned short h){
  union { unsigned u; float f; } v; v.u = ((unsigned)h) << 16; return v.f;
}
__device__ __forceinline__ int clampi(int v){
  return v < 0 ? 0 : (v >= N_NODES ? N_NODES - 1 : v);
}

// ---------------- weight transpose + bf16 convert ----------------
struct TJob { const float* in; unsigned short* out; int K; int N; int row0; int ld; };
struct TJobs { TJob j[12]; };

__global__ __launch_bounds__(256) void prep_weights(TJobs jobs){
  TJob jb = jobs.j[blockIdx.y];
  int total = jb.K * jb.N;
  int i = blockIdx.x * 256 + threadIdx.x;
  if (i >= total) return;
  int n = i / jb.K;
  int k = i - n * jb.K;
  jb.out[(size_t)n * jb.K + k] = f2bf(jb.in[(size_t)(jb.row0 + k) * jb.ld + n]);
}

// ---------------- counting sort of edges by dst ----------------
__global__ __launch_bounds__(256) void hist_k(const int* __restrict__ ei, int* __restrict__ HIST){
  int e = blockIdx.x * 256 + threadIdx.x;
  if (e < N_EDGES) atomicAdd(&HIST[clampi(ei[N_EDGES + e])], 1);
}

__global__ __launch_bounds__(1024) void scan_k(const int* __restrict__ HIST,
                                               int* __restrict__ OFFW,
                                               float* __restrict__ CNTf){
  __shared__ int ps[1024];
  const int t = threadIdx.x;
  int loc[10]; int s = 0;
  #pragma unroll
  for (int i = 0; i < 10; i++){
    int idx = t * 10 + i;
    int v = (idx < N_NODES) ? HIST[idx] : 0;
    loc[i] = s; s += v;
  }
  ps[t] = s; __syncthreads();
  const int mine = s;
  for (int o = 1; o < 1024; o <<= 1){
    int v = (t >= o) ? ps[t - o] : 0;
    __syncthreads();
    ps[t] += v;
    __syncthreads();
  }
  const int excl = ps[t] - mine;
  #pragma unroll
  for (int i = 0; i < 10; i++){
    int idx = t * 10 + i;
    if (idx < N_NODES){
      OFFW[idx] = excl + loc[i];
      CNTf[idx] = (float)HIST[idx];
    }
  }
}

__global__ __launch_bounds__(256) void perm_k(const int* __restrict__ ei,
                                              int* __restrict__ OFFW,
                                              int* __restrict__ perm){
  int e = blockIdx.x * 256 + threadIdx.x;
  if (e < N_EDGES){
    int d = clampi(ei[N_EDGES + e]);
    int pos = atomicAdd(&OFFW[d], 1);
    perm[pos] = e;
  }
}

// ---- MFMA over a [ROWS][256] bf16 LDS tile, per-wave 32x64 output ----------
// A: LDS XOR-swizzled: byte = row*512 + (colbyte ^ ((row&7)<<4))
// Wt: row-major [outCols][wstride] bf16. Wave w computes cols w*64..w*64+63.
__device__ __forceinline__ void mfma_tiles32(const unsigned short* __restrict__ A,
                                             const unsigned short* __restrict__ Wt,
                                             int wstride, int l, int w, f32x4 acc[2][4])
{
  #pragma unroll
  for (int ks = 0; ks < 8; ks++){
    const int kb = ks * 64 + ((l >> 4) << 4);     // byte offset of this lane's 8 bf16
    bf16x8 a[2];
    #pragma unroll
    for (int mi = 0; mi < 2; mi++){
      const int row = mi * 16 + (l & 15);
      a[mi] = *(const bf16x8*)((const char*)A + row * 512 + (kb ^ ((row & 7) << 4)));
    }
    #pragma unroll
    for (int ni = 0; ni < 4; ni++){
      const unsigned short* bp = Wt + (size_t)((w * 4 + ni) * 16 + (l & 15)) * wstride;
      bf16x8 b = *(const bf16x8*)((const char*)bp + kb);
      #pragma unroll
      for (int mi = 0; mi < 2; mi++)
        acc[mi][ni] = __builtin_amdgcn_mfma_f32_16x16x32_bf16(a[mi], b, acc[mi][ni], 0, 0, 0);
    }
  }
}
__device__ __forceinline__ void zero_acc32(f32x4 acc[2][4]){
  #pragma unroll
  for (int mi = 0; mi < 2; mi++)
    #pragma unroll
    for (int ni = 0; ni < 4; ni++)
      acc[mi][ni] = (f32x4){0.f, 0.f, 0.f, 0.f};
}

// ---- 64-row variant for node GEMMs ---------
__device__ __forceinline__ void mfma_tiles64(const unsigned short* __restrict__ A,
                                             const unsigned short* __restrict__ Wt,
                                             int wstride, int l, int w, f32x4 acc[4][4])
{
  #pragma unroll
  for (int ks = 0; ks < 8; ks++){
    const int kb = ks * 64 + ((l >> 4) << 4);
    bf16x8 a[4];
    #pragma unroll
    for (int mi = 0; mi < 4; mi++){
      const int row = mi * 16 + (l & 15);
      a[mi] = *(const bf16x8*)((const char*)A + row * 512 + (kb ^ ((row & 7) << 4)));
    }
    #pragma unroll
    for (int ni = 0; ni < 4; ni++){
      const unsigned short* bp = Wt + (size_t)((w * 4 + ni) * 16 + (l & 15)) * wstride;
      bf16x8 b = *(const bf16x8*)((const char*)bp + kb);
      #pragma unroll
      for (int mi = 0; mi < 4; mi++)
        acc[mi][ni] = __builtin_amdgcn_mfma_f32_16x16x32_bf16(a[mi], b, acc[mi][ni], 0, 0, 0);
    }
  }
}

// ---------------- generic node GEMM: C = act([A1|A2/cnt] @ Wt + bias) -------
__global__ __launch_bounds__(256) void gemm_nodes(
    const float* __restrict__ A1, int K1,
    const float* __restrict__ A2, int K2,
    const unsigned short* __restrict__ Wt,   // [NcTot][Ktot]
    const float* __restrict__ bias,
    void* __restrict__ Cout, int NcTot, int relu, int out_bf16,
    const float* __restrict__ cnt)           // if set: divide A2 rows by max(cnt,1)
{
  __shared__ __align__(16) unsigned short As[64 * 256];
  const int t = threadIdx.x, w = t >> 6, l = t & 63;
  const int rowBase = blockIdx.x * 64;
  const int bc = blockIdx.y;
  const int Ktot = K1 + K2;
  f32x4 acc[4][4] = {};
  for (int kc = 0; kc < Ktot; kc += 256){
    __syncthreads();
    {
      const int r = t >> 2, q = t & 3;
      int rg = rowBase + r; if (rg >= N_NODES) rg = N_NODES - 1;
      const int inA2 = (kc >= K1);
      const float* src = !inA2 ? (A1 + (size_t)rg * K1 + kc)
                               : (A2 + (size_t)rg * K2 + (kc - K1));
      const float inv = (cnt && inA2) ? (1.f / fmaxf(cnt[rg], 1.f)) : 1.f;
      #pragma unroll
      for (int u = 0; u < 16; u++){
        const int cb = q * 128 + u * 8;
        f32x4 v = *(const f32x4*)(src + q * 64 + u * 4);
        ushort4v h;
        h[0] = f2bf(v[0] * inv); h[1] = f2bf(v[1] * inv);
        h[2] = f2bf(v[2] * inv); h[3] = f2bf(v[3] * inv);
        *(ushort4v*)((char*)As + r * 512 + (cb ^ ((r & 7) << 4))) = h;
      }
    }
    __syncthreads();
    mfma_tiles64(As, Wt + (size_t)(bc * 256) * Ktot + kc, Ktot, l, w, acc);
  }
  #pragma unroll
  for (int mi = 0; mi < 4; mi++)
  #pragma unroll
  for (int ni = 0; ni < 4; ni++){
    const int colAbs = bc * 256 + (w * 4 + ni) * 16 + (l & 15);
    const float bv = bias ? bias[colAbs] : 0.f;
    #pragma unroll
    for (int r = 0; r < 4; r++){
      const int rowg = rowBase + mi * 16 + (l >> 4) * 4 + r;
      if (rowg < N_NODES){
        float v = acc[mi][ni][r] + bv;
        if (relu) v = fmaxf(v, 0.f);
        if (out_bf16) ((unsigned short*)Cout)[(size_t)rowg * NcTot + colAbs] = f2bf(v);
        else          ((float*)Cout)[(size_t)rowg * NcTot + colAbs] = v;
      }
    }
  }
}

// ---------------- layer-0 fused edge pass (dst-sorted, segmented scatter) ---
// Processes edges in dst-sorted order (perm). Per 32-edge tile:
//   EH = relu(pA0[src] + pB0[dst] + ea@W1c + b1)      -> B
//   ea1 = EH @ e_w2_0 + b2                            -> B, copy to EA1s (SORTED order)
//   msg = relu(ea1 @ Wm_e + pM0[src] + bm)            -> B
//   column-wise segmented sum over dst-runs -> few atomics into S
__global__ __launch_bounds__(256, 4) void edge_pass0(
    const int* __restrict__ ei,
    const float* __restrict__ ea,
    const unsigned short* __restrict__ P0h,  // [N][768] bf16 = pA0|pB0|pM0
    const float* __restrict__ W1c,           // [6][256] f32
    const float* __restrict__ b1,
    const unsigned short* __restrict__ Wt_ew2,
    const float* __restrict__ b2,
    const unsigned short* __restrict__ Wt_wme,
    const float* __restrict__ bm,
    const int* __restrict__ perm,
    unsigned short* __restrict__ EA1s,       // [E][256] bf16, dst-SORTED edge order
    float* __restrict__ S)
{
  __shared__ __align__(16) unsigned short B[EROWS * 256];
  __shared__ int eids[EROWS];
  __shared__ int dsts[EROWS];
  const int t = threadIdx.x, w = t >> 6, l = t & 63;
  const int p0 = blockIdx.x * EROWS;
  if (t < EROWS){
    const int e = perm[p0 + t];
    eids[t] = e;
    dsts[t] = clampi(ei[N_EDGES + e]);
  }
  __syncthreads();
  // phase E: EH -> B   (8 threads per edge row, 32 cols each)
  {
    const int r = t >> 3, q = t & 7;
    const int e = eids[r];
    const int sv = clampi(ei[e]);
    const int dv = dsts[r];
    const unsigned short* pa = P0h + (size_t)sv * 768;
    const unsigned short* pb = P0h + (size_t)dv * 768 + 256;
    float eav[6];
    #pragma unroll
    for (int k = 0; k < 6; k++) eav[k] = ea[(size_t)e * 6 + k];
    #pragma unroll
    for (int u = 0; u < 4; u++){
      const int c = q * 32 + u * 8;
      bf16x8 va = *(const bf16x8*)(pa + c);
      bf16x8 vb = *(const bf16x8*)(pb + c);
      bf16x8 h;
      #pragma unroll
      for (int j = 0; j < 8; j++){
        float v = bf2f((unsigned short)va[j]) + bf2f((unsigned short)vb[j]) + b1[c + j];
        #pragma unroll
        for (int k = 0; k < 6; k++) v += eav[k] * W1c[k * 256 + c + j];
        h[j] = (short)f2bf(fmaxf(v, 0.f));
      }
      *(bf16x8*)((char*)B + r * 512 + ((2 * c) ^ ((r & 7) << 4))) = h;
    }
  }
  __syncthreads();
  // GEMM1: ea1 in acc
  f32x4 acc[2][4];
  zero_acc32(acc);
  mfma_tiles32(B, Wt_ew2, 256, l, w, acc);
  __syncthreads();                     // all reads of EH done
  // write ea1 back into B (same swizzled layout)
  #pragma unroll
  for (int mi = 0; mi < 2; mi++)
  #pragma unroll
  for (int ni = 0; ni < 4; ni++){
    const int col = (w * 4 + ni) * 16 + (l & 15);
    const float bb = b2[col];
    #pragma unroll
    for (int r = 0; r < 4; r++){
      const int row = mi * 16 + (l >> 4) * 4 + r;
      *(unsigned short*)((char*)B + row * 512 + ((2 * col) ^ ((row & 7) << 4)))
          = f2bf(acc[mi][ni][r] + bb);
    }
  }
  __syncthreads();
  // copy B -> EA1s at SORTED position (fully linear, coalesced)
  {
    const int r = t >> 3, q = t & 7;
    char* gdst = (char*)EA1s + (size_t)(p0 + r) * 512 + q * 64;
    #pragma unroll
    for (int u = 0; u < 4; u++){
      const int cb = q * 64 + u * 16;
      *(bf16x8*)(gdst + u * 16) =
        *(const bf16x8*)((const char*)B + r * 512 + (cb ^ ((r & 7) << 4)));
    }
  }
  // GEMM2: msg
  zero_acc32(acc);
  mfma_tiles32(B, Wt_wme, 256, l, w, acc);
  __syncthreads();                     // all reads of ea1 done (copy + mfma)
  // write msg into B (with pM0 gather + relu)
  #pragma unroll
  for (int mi = 0; mi < 2; mi++)
  #pragma unroll
  for (int ni = 0; ni < 4; ni++){
    const int col = (w * 4 + ni) * 16 + (l & 15);
    const float bb = bm[col];
    #pragma unroll
    for (int r = 0; r < 4; r++){
      const int row = mi * 16 + (l >> 4) * 4 + r;
      const int sv = clampi(ei[eids[row]]);
      float v = acc[mi][ni][r] + bb + bf2f(P0h[(size_t)sv * 768 + 512 + col]);
      *(unsigned short*)((char*)B + row * 512 + ((2 * col) ^ ((row & 7) << 4)))
          = f2bf(fmaxf(v, 0.f));
    }
  }
  __syncthreads();
  // column-wise segmented reduction over dst-runs (thread = column; branches
  // are wave-uniform since dsts[r] is the same for all lanes)
  {
    const int col = t;
    float sum = 0.f;
    int cur = dsts[0];
    for (int r = 0; r < EROWS; r++){
      const int d = dsts[r];
      if (d != cur){
        atomicAdd(&S[(size_t)cur * 256 + col], sum);
        sum = 0.f; cur = d;
      }
      sum += bf2f(*(const unsigned short*)((const char*)B + r * 512 + ((2 * col) ^ ((r & 7) << 4))));
    }
    atomicAdd(&S[(size_t)cur * 256 + col], sum);
  }
}

// ---------------- layer-1 fused edge pass + predictor head -------------------
// Processes edges in dst-sorted order (EA1s is sorted). Two LDS tiles:
// B1 holds ea1 then ea2 (residual read in-place, no register cache -> no spill);
// B2 holds eh1.
//   eh1 = relu(ea1 @ W1c1 + pA1[src] + pB1[dst] + b1)    B1 -> B2
//   ea2 = eh1 @ e_w2_1 + b2 + ea1                        B2 -> B1 (in-place res)
//   out[orig e] = relu(ea2 @ p_w1 + p_b1) . p_w2 + p_b2  B1 -> scatter
__global__ __launch_bounds__(256, 4) void edge_pass1(
    const int* __restrict__ ei,
    const unsigned short* __restrict__ EA1s,
    const int* __restrict__ perm,
    const unsigned short* __restrict__ P1h,  // [N][512] bf16 = pA1|pB1
    const float* __restrict__ b1,            // e_b1_1
    const unsigned short* __restrict__ Wt_w1c,
    const unsigned short* __restrict__ Wt_ew2,
    const float* __restrict__ b2,            // e_b2_1
    const unsigned short* __restrict__ Wt_pw1,
    const float* __restrict__ pb1,
    const float* __restrict__ pw2,
    const float* __restrict__ pb2,
    float* __restrict__ out)
{
  __shared__ __align__(16) unsigned short B1[EROWS * 256];
  __shared__ __align__(16) unsigned short B2[EROWS * 256];
  __shared__ float partial[128];
  __shared__ int eids[EROWS];
  const int t = threadIdx.x, w = t >> 6, l = t & 63;
  const int p0 = blockIdx.x * EROWS;
  if (t < EROWS) eids[t] = perm[p0 + t];
  // load ea1 tile (sorted, linear) -> B1 (swizzled)
  {
    const int r = t >> 3, q = t & 7;
    const char* gsrc = (const char*)EA1s + (size_t)(p0 + r) * 512 + q * 64;
    #pragma unroll
    for (int u = 0; u < 4; u++){
      const int cb = q * 64 + u * 16;
      *(bf16x8*)((char*)B1 + r * 512 + (cb ^ ((r & 7) << 4))) = *(const bf16x8*)(gsrc + u * 16);
    }
  }
  __syncthreads();
  // GEMM_a: eh1 = relu(ea1 @ W1c1 + gathers + b1)  -> B2
  f32x4 acc[2][4];
  zero_acc32(acc);
  mfma_tiles32(B1, Wt_w1c, 256, l, w, acc);
  #pragma unroll
  for (int mi = 0; mi < 2; mi++)
  #pragma unroll
  for (int ni = 0; ni < 4; ni++){
    const int col = (w * 4 + ni) * 16 + (l & 15);
    const float bb = b1[col];
    #pragma unroll
    for (int r = 0; r < 4; r++){
      const int row = mi * 16 + (l >> 4) * 4 + r;
      const int e = eids[row];
      const int sv = clampi(ei[e]);
      const int dv = clampi(ei[N_EDGES + e]);
      float v = acc[mi][ni][r] + bb + bf2f(P1h[(size_t)sv * 512 + col])
              + bf2f(P1h[(size_t)dv * 512 + 256 + col]);
      *(unsigned short*)((char*)B2 + row * 512 + ((2 * col) ^ ((row & 7) << 4)))
          = f2bf(fmaxf(v, 0.f));
    }
  }
  __syncthreads();
  // GEMM_b: ea2 = eh1 @ W2 + b2 + ea1   (reads B2; residual read from B1
  // in-place — each cell is read+written by its unique owner thread)
  zero_acc32(acc);
  mfma_tiles32(B2, Wt_ew2, 256, l, w, acc);
  #pragma unroll
  for (int mi = 0; mi < 2; mi++)
  #pragma unroll
  for (int ni = 0; ni < 4; ni++){
    const int col = (w * 4 + ni) * 16 + (l & 15);
    const float bb = b2[col];
    #pragma unroll
    for (int r = 0; r < 4; r++){
      const int row = mi * 16 + (l >> 4) * 4 + r;
      unsigned short* p = (unsigned short*)((char*)B1 + row * 512 + ((2 * col) ^ ((row & 7) << 4)));
      *p = f2bf(acc[mi][ni][r] + bb + bf2f(*p));
    }
  }
  __syncthreads();
  // GEMM_c: h = relu(ea2 @ p_w1 + pb1); rowsum(h * pw2)
  zero_acc32(acc);
  mfma_tiles32(B1, Wt_pw1, 256, l, w, acc);
  {
    float rs[2][4];
    #pragma unroll
    for (int mi = 0; mi < 2; mi++)
      #pragma unroll
      for (int r = 0; r < 4; r++) rs[mi][r] = 0.f;
    #pragma unroll
    for (int mi = 0; mi < 2; mi++)
    #pragma unroll
    for (int ni = 0; ni < 4; ni++){
      const int col = (w * 4 + ni) * 16 + (l & 15);
      const float pb = pb1[col];
      const float pw = pw2[col];
      #pragma unroll
      for (int r = 0; r < 4; r++)
        rs[mi][r] += fmaxf(acc[mi][ni][r] + pb, 0.f) * pw;
    }
    #pragma unroll
    for (int off = 1; off < 16; off <<= 1){
      #pragma unroll
      for (int mi = 0; mi < 2; mi++)
        #pragma unroll
        for (int r = 0; r < 4; r++)
          rs[mi][r] += __shfl_xor(rs[mi][r], off);
    }
    if ((l & 15) == 0){
      #pragma unroll
      for (int mi = 0; mi < 2; mi++)
        #pragma unroll
        for (int r = 0; r < 4; r++)
          partial[w * 32 + mi * 16 + (l >> 4) * 4 + r] = rs[mi][r];
    }
  }
  __syncthreads();
  if (t < EROWS)
    out[eids[t]] = partial[t] + partial[32 + t] + partial[64 + t] + partial[96 + t] + pb2[0];
}

// ---------------- host ----------------
extern "C" void kernel_launch(void* const* d_in, const int* in_sizes, int n_in,
                              void* d_out, int out_size, void* d_ws, size_t ws_size,
                              hipStream_t stream)
{
  const float* x      = (const float*)d_in[0];
  const int* ei       = (const int*)d_in[1];        // int32 per harness contract
  const float* eattr  = (const float*)d_in[2];
  const float* e_w1_0 = (const float*)d_in[3];
  const float* e_b1_0 = (const float*)d_in[4];
  const float* e_w2_0 = (const float*)d_in[5];
  const float* e_b2_0 = (const float*)d_in[6];
  const float* n_wm_0 = (const float*)d_in[7];
  const float* n_bm_0 = (const float*)d_in[8];
  const float* n_w1_0 = (const float*)d_in[9];
  const float* n_b1_0 = (const float*)d_in[10];
  const float* n_w2_0 = (const float*)d_in[11];
  const float* n_b2_0 = (const float*)d_in[12];
  const float* e_w1_1 = (const float*)d_in[13];
  const float* e_b1_1 = (const float*)d_in[14];
  const float* e_w2_1 = (const float*)d_in[15];
  const float* e_b2_1 = (const float*)d_in[16];
  // d_in[17..22] (layer-1 node model) are dead code for the output
  const float* p_w1   = (const float*)d_in[23];
  const float* p_b1   = (const float*)d_in[24];
  const float* p_w2   = (const float*)d_in[25];
  const float* p_b2   = (const float*)d_in[26];
  float* out = (float*)d_out;

  char* base = (char*)d_ws;
  size_t off = 0;
  auto take = [&](size_t bytes)->void*{
    void* p = base + off;
    off = (off + bytes + 255) & ~(size_t)255;
    return p;
  };
  unsigned short* WtP0   = (unsigned short*)take((size_t)768 * 512 * 2);
  unsigned short* Wtew20 = (unsigned short*)take((size_t)256 * 256 * 2);
  unsigned short* Wtwme0 = (unsigned short*)take((size_t)256 * 256 * 2);
  unsigned short* Wtnw1  = (unsigned short*)take((size_t)256 * 768 * 2);
  unsigned short* Wtnw2  = (unsigned short*)take((size_t)256 * 256 * 2);
  unsigned short* WtP1   = (unsigned short*)take((size_t)512 * 256 * 2);
  unsigned short* Wtw1c1 = (unsigned short*)take((size_t)256 * 256 * 2);
  unsigned short* Wtew21 = (unsigned short*)take((size_t)256 * 256 * 2);
  unsigned short* Wtpw1  = (unsigned short*)take((size_t)256 * 256 * 2);
  // Region A (15.36MB): P0h (bf16 [10000][768]) lives here during layer 0.
  // After edge_pass0 it is dead: NH (f32) overlays it, then P1h overlays again.
  char* regionA = (char*)take((size_t)N_NODES * 768 * 2);
  unsigned short* P0h = (unsigned short*)regionA;
  float* NH           = (float*)regionA;
  unsigned short* P1h = (unsigned short*)regionA;
  float* S   = (float*)take((size_t)N_NODES * 256 * 4);
  float* X1  = S;    // X1 computed after S is dead
  float* CNTf = (float*)take((size_t)N_NODES * 4);
  unsigned short* EA1s = (unsigned short*)take((size_t)N_EDGES * 256 * 2);
  int* HIST = (int*)take((size_t)N_NODES * 4);
  int* OFFW = (int*)take((size_t)N_NODES * 4);
  int* perm = (int*)take((size_t)N_EDGES * 4);
  (void)ws_size; (void)in_sizes; (void)n_in; (void)out_size;

  TJobs jobs;
  auto J = [&](int idx, const float* in, unsigned short* outp, int K, int N, int row0, int ld){
    jobs.j[idx].in = in; jobs.j[idx].out = outp; jobs.j[idx].K = K;
    jobs.j[idx].N = N; jobs.j[idx].row0 = row0; jobs.j[idx].ld = ld;
  };
  J(0,  e_w1_0, WtP0,            512, 256,   0, 256);  // pA0
  J(1,  e_w1_0, WtP0 + 256*512,  512, 256, 512, 256);  // pB0
  J(2,  n_wm_0, WtP0 + 512*512,  512, 256,   0, 256);  // pM0
  J(3,  e_w2_0, Wtew20, 256, 256,   0, 256);
  J(4,  n_wm_0, Wtwme0, 256, 256, 512, 256);
  J(5,  n_w1_0, Wtnw1,  768, 256,   0, 256);
  J(6,  n_w2_0, Wtnw2,  256, 256,   0, 256);
  J(7,  e_w1_1, WtP1,            256, 256,   0, 256);  // pA1
  J(8,  e_w1_1, WtP1 + 256*256,  256, 256, 256, 256);  // pB1
  J(9,  e_w1_1, Wtw1c1, 256, 256, 512, 256);
  J(10, e_w2_1, Wtew21, 256, 256,   0, 256);
  J(11, p_w1,   Wtpw1,  256, 256,   0, 256);
  prep_weights<<<dim3(768, 12), 256, 0, stream>>>(jobs);

  hipMemsetAsync(S, 0, (size_t)N_NODES * 256 * 4, stream);
  hipMemsetAsync(HIST, 0, (size_t)N_NODES * 4, stream);

  // ---- counting sort of edges by dst ----
  hist_k<<<(N_EDGES + 255) / 256, 256, 0, stream>>>(ei, HIST);
  scan_k<<<1, 1024, 0, stream>>>(HIST, OFFW, CNTf);
  perm_k<<<(N_EDGES + 255) / 256, 256, 0, stream>>>(ei, OFFW, perm);

  const int NT = (N_NODES + 63) / 64;   // 157
  // P0h = bf16( x @ [pA0|pB0|pM0] )
  gemm_nodes<<<dim3(NT, 3), 256, 0, stream>>>(x, 512, nullptr, 0, WtP0, nullptr, P0h, 768, 0, 1, nullptr);
  edge_pass0<<<N_EDGES / EROWS, 256, 0, stream>>>(ei, eattr, P0h, e_w1_0 + 1024 * 256, e_b1_0,
                                                  Wtew20, e_b2_0, Wtwme0, n_bm_0, perm, EA1s, S);
  // NH = relu([x | S/cnt] @ n_w1_0 + b)   (mean-normalize fused; NH overlays dead P0h)
  gemm_nodes<<<dim3(NT, 1), 256, 0, stream>>>(x, 512, S, 256, Wtnw1, n_b1_0, NH, 256, 1, 0, CNTf);
  // X1 = NH @ n_w2_0 + b                  (X1 overlays dead S)
  gemm_nodes<<<dim3(NT, 1), 256, 0, stream>>>(NH, 256, nullptr, 0, Wtnw2, n_b2_0, X1, 256, 0, 0, nullptr);
  // P1h = bf16( X1 @ [pA1|pB1] )          (overlays region A after NH is consumed)
  gemm_nodes<<<dim3(NT, 2), 256, 0, stream>>>(X1, 256, nullptr, 0, WtP1, nullptr, P1h, 512, 0, 1, nullptr);
  edge_pass1<<<N_EDGES / EROWS, 256, 0, stream>>>(ei, EA1s, perm, P1h, e_b1_1, Wtw1c1, Wtew21,
                                                  e_b2_1, Wtpw1, p_b1, p_w2, p_b2, out);
}